// Round 1
// baseline (142.700 us; speedup 1.0000x reference)
//
#include <hip/hip_runtime.h>
#include <math.h>

#define N_BATCH 2
#define C_CH    256
#define H_IMG   64
#define W_IMG   64
#define S_SAMP  64
#define HW      (H_IMG * W_IMG)

// det of 3x3 with columns u, v, w
__device__ __forceinline__ double det3(const double* u, const double* v, const double* w) {
    return u[0] * (v[1] * w[2] - v[2] * w[1])
         - v[0] * (u[1] * w[2] - u[2] * w[1])
         + w[0] * (u[1] * v[2] - u[2] * v[1]);
}

// Compute fundamental matrix F = skew(P2 @ Cc) @ P2 @ pinv(P1) per batch, fp64.
// Cc = unit-norm null vector of P1 (== eigh(P1^T P1) smallest eigenvector, up to sign,
// and the sign cancels downstream). pinv(P1) = P1^T (P1 P1^T)^{-1} (full row rank).
__global__ void compute_F_kernel(const float* __restrict__ P1g,
                                 const float* __restrict__ P2g,
                                 double* __restrict__ Fout) {
    int n = threadIdx.x;
    if (n >= N_BATCH) return;
    double p1[3][4], p2[3][4];
    for (int i = 0; i < 3; i++)
        for (int j = 0; j < 4; j++) {
            p1[i][j] = (double)P1g[n * 12 + i * 4 + j];
            p2[i][j] = (double)P2g[n * 12 + i * 4 + j];
        }
    // columns of P1
    double col[4][3];
    for (int j = 0; j < 4; j++)
        for (int i = 0; i < 3; i++) col[j][i] = p1[i][j];
    // null vector via signed 3x3 minors (generalized cross product of rows)
    const int idx[4][3] = {{1,2,3},{0,2,3},{0,1,3},{0,1,2}};
    double v[4];
    double sgn = 1.0;
    for (int j = 0; j < 4; j++) {
        v[j] = sgn * det3(col[idx[j][0]], col[idx[j][1]], col[idx[j][2]]);
        sgn = -sgn;
    }
    double nrm = sqrt(v[0]*v[0] + v[1]*v[1] + v[2]*v[2] + v[3]*v[3]);
    for (int j = 0; j < 4; j++) v[j] /= nrm;
    // epipole e2 = P2 @ v
    double e2[3];
    for (int i = 0; i < 3; i++)
        e2[i] = p2[i][0]*v[0] + p2[i][1]*v[1] + p2[i][2]*v[2] + p2[i][3]*v[3];
    // A = P1 P1^T (3x3), invert via adjugate
    double A[3][3];
    for (int i = 0; i < 3; i++)
        for (int k = 0; k < 3; k++) {
            double s = 0.0;
            for (int j = 0; j < 4; j++) s += p1[i][j] * p1[k][j];
            A[i][k] = s;
        }
    double det = A[0][0]*(A[1][1]*A[2][2] - A[1][2]*A[2][1])
               - A[0][1]*(A[1][0]*A[2][2] - A[1][2]*A[2][0])
               + A[0][2]*(A[1][0]*A[2][1] - A[1][1]*A[2][0]);
    double Ai[3][3];
    Ai[0][0] =  (A[1][1]*A[2][2] - A[1][2]*A[2][1]) / det;
    Ai[0][1] = -(A[0][1]*A[2][2] - A[0][2]*A[2][1]) / det;
    Ai[0][2] =  (A[0][1]*A[1][2] - A[0][2]*A[1][1]) / det;
    Ai[1][0] = -(A[1][0]*A[2][2] - A[1][2]*A[2][0]) / det;
    Ai[1][1] =  (A[0][0]*A[2][2] - A[0][2]*A[2][0]) / det;
    Ai[1][2] = -(A[0][0]*A[1][2] - A[0][2]*A[1][0]) / det;
    Ai[2][0] =  (A[1][0]*A[2][1] - A[1][1]*A[2][0]) / det;
    Ai[2][1] = -(A[0][0]*A[2][1] - A[0][1]*A[2][0]) / det;
    Ai[2][2] =  (A[0][0]*A[1][1] - A[0][1]*A[1][0]) / det;
    // B = P2 P1^T (3x3); G = P2 @ pinv(P1) = B @ Ai
    double B[3][3];
    for (int i = 0; i < 3; i++)
        for (int m = 0; m < 3; m++) {
            double s = 0.0;
            for (int k = 0; k < 4; k++) s += p2[i][k] * p1[m][k];
            B[i][m] = s;
        }
    double G[3][3];
    for (int i = 0; i < 3; i++)
        for (int j = 0; j < 3; j++)
            G[i][j] = B[i][0]*Ai[0][j] + B[i][1]*Ai[1][j] + B[i][2]*Ai[2][j];
    // F = skew(e2) @ G
    double F[3][3];
    for (int j = 0; j < 3; j++) {
        F[0][j] = -e2[2]*G[1][j] + e2[1]*G[2][j];
        F[1][j] =  e2[2]*G[0][j] - e2[0]*G[2][j];
        F[2][j] = -e2[1]*G[0][j] + e2[0]*G[1][j];
    }
    for (int i = 0; i < 3; i++)
        for (int j = 0; j < 3; j++) Fout[n * 9 + i * 3 + j] = F[i][j];
}

// (N,C,H,W) -> (N,H*W,C) transpose so channels are contiguous (coalesced gathers)
__global__ void transpose_kernel(const float* __restrict__ in, float* __restrict__ outp) {
    __shared__ float tile[32][33];
    const int n  = blockIdx.z;
    const int p0 = blockIdx.x * 32;
    const int c0 = blockIdx.y * 32;
    for (int i = threadIdx.y; i < 32; i += 8)
        tile[i][threadIdx.x] = in[((size_t)n * C_CH + c0 + i) * HW + p0 + threadIdx.x];
    __syncthreads();
    for (int i = threadIdx.y; i < 32; i += 8)
        outp[((size_t)n * HW + p0 + i) * C_CH + c0 + threadIdx.x] = tile[threadIdx.x][i];
}

// One wave (64 lanes) per pixel. Lane s precomputes tap offsets/weights for sample s
// into LDS; then each lane owns 4 channels (float4) and maxes over the 64 samples.
template <bool TRANS>
__global__ __launch_bounds__(64) void sample_max_kernel(const float* __restrict__ feat,
                                                        const double* __restrict__ Fm,
                                                        float* __restrict__ out) {
    const int bid  = blockIdx.x;
    const int n    = bid >> 12;   // / 4096
    const int p    = bid & 4095;
    const int h    = p >> 6;
    const int w    = p & 63;
    const int lane = threadIdx.x;

    __shared__ int4   s_off[S_SAMP];
    __shared__ float4 s_wt[S_SAMP];

    {
        const double* F = Fm + n * 9;
        const double wd = (double)w, hd = (double)h;
        const double a = F[0]*wd + F[1]*hd + F[2];
        const double b = F[3]*wd + F[4]*hd + F[5];
        const double c = F[6]*wd + F[7]*hd + F[8];
        const double EPSd = 0.001;
        const double xmaxv = 63.0, ymaxv = 63.0;
        const double sb = (b > 0.0) ? 1.0 : ((b < 0.0) ? -1.0 : 0.0);
        const double sa = (a > 0.0) ? 1.0 : ((a < 0.0) ? -1.0 : 0.0);
        const double db = sb * fmax(fabs(b), EPSd);
        const double da = sa * fmax(fabs(a), EPSd);
        const double by1 = -c / db;                  // xmin = 0
        const double by2 = -(xmaxv * a + c) / db;
        const double bx0 = -c / da;                  // ymin = 0
        const double bx3 = -(ymaxv * b + c) / da;
        const double PX[4] = {bx0, 0.0, xmaxv, bx3};
        const double PY[4] = {0.0, by1, by2, ymaxv};
        bool m[4];
        m[0] = (bx0 >= EPSd) && (bx0 <  xmaxv - EPSd);
        m[1] = (by1 >  EPSd) && (by1 <= ymaxv - EPSd);
        m[2] = (by2 >= EPSd) && (by2 <  ymaxv - EPSd);
        m[3] = (bx3 >  EPSd) && (bx3 <= xmaxv - EPSd);
        const int nint = (int)m[0] + (int)m[1] + (int)m[2] + (int)m[3];
        const bool valid2 = (nint >= 2);
        bool tm[4];
        if (valid2) { tm[0]=m[0]; tm[1]=m[1]; tm[2]=m[2]; tm[3]=m[3]; }
        else        { tm[0]=true; tm[1]=true; tm[2]=false; tm[3]=false; }
        // stable argsort of (tm?i:4+i): true indices ascending, then false ascending
        int i0 = -1, i1 = -1;
        for (int i = 0; i < 4; i++) if (tm[i])  { if (i0 < 0) i0 = i; else if (i1 < 0) i1 = i; }
        for (int i = 0; i < 4; i++) if (!tm[i]) { if (i0 < 0) i0 = i; else if (i1 < 0) i1 = i; }
        double sx, sy, vx, vy;
        if (valid2) { sx = PX[i0]; sy = PY[i0]; vx = PX[i1] - sx; vy = PY[i1] - sy; }
        else        { sx = -10000.0; sy = -10000.0; vx = 0.0; vy = 0.0; }

        // lane == sample index s
        const double t  = (double)lane / 63.0;
        const double lx = sx + vx * t;
        const double ly = sy + vy * t;
        const double gx = lx / 63.0 * 2.0 - 1.0;
        const double gy = ly / 63.0 * 2.0 - 1.0;
        const double x  = (gx + 1.0) * 32.0 - 0.5;
        const double y  = (gy + 1.0) * 32.0 - 0.5;
        const double x0 = floor(x), y0 = floor(y);
        const double wx = x - x0,  wy = y - y0;
        const double wt4[4] = {(1.0-wx)*(1.0-wy), wx*(1.0-wy), (1.0-wx)*wy, wx*wy};
        int   offs[4];
        float wts[4];
        #pragma unroll
        for (int k = 0; k < 4; k++) {
            const double ix = x0 + (double)(k & 1);
            const double iy = y0 + (double)(k >> 1);
            const bool val = (ix >= 0.0) && (ix < 64.0) && (iy >= 0.0) && (iy < 64.0);
            const double ixc = fmin(fmax(ix, 0.0), 63.0);
            const double iyc = fmin(fmax(iy, 0.0), 63.0);
            offs[k] = ((int)iyc) * 64 + (int)ixc;   // unscaled pixel offset
            wts[k]  = val ? (float)wt4[k] : 0.0f;
        }
        s_off[lane] = make_int4(offs[0], offs[1], offs[2], offs[3]);
        s_wt[lane]  = make_float4(wts[0], wts[1], wts[2], wts[3]);
    }
    __syncthreads();

    const float* base = feat + (size_t)n * (size_t)HW * C_CH;
    float mx0 = -INFINITY, mx1 = -INFINITY, mx2 = -INFINITY, mx3 = -INFINITY;
    const int cb = lane * 4;
    #pragma unroll 4
    for (int s = 0; s < S_SAMP; s++) {
        const int4   o  = s_off[s];
        const float4 wv = s_wt[s];
        float4 v0, v1, v2, v3;
        if constexpr (TRANS) {
            v0 = *(const float4*)(base + o.x * C_CH + cb);
            v1 = *(const float4*)(base + o.y * C_CH + cb);
            v2 = *(const float4*)(base + o.z * C_CH + cb);
            v3 = *(const float4*)(base + o.w * C_CH + cb);
        } else {
            v0 = make_float4(base[(size_t)(cb+0)*HW + o.x], base[(size_t)(cb+1)*HW + o.x],
                             base[(size_t)(cb+2)*HW + o.x], base[(size_t)(cb+3)*HW + o.x]);
            v1 = make_float4(base[(size_t)(cb+0)*HW + o.y], base[(size_t)(cb+1)*HW + o.y],
                             base[(size_t)(cb+2)*HW + o.y], base[(size_t)(cb+3)*HW + o.y]);
            v2 = make_float4(base[(size_t)(cb+0)*HW + o.z], base[(size_t)(cb+1)*HW + o.z],
                             base[(size_t)(cb+2)*HW + o.z], base[(size_t)(cb+3)*HW + o.z]);
            v3 = make_float4(base[(size_t)(cb+0)*HW + o.w], base[(size_t)(cb+1)*HW + o.w],
                             base[(size_t)(cb+2)*HW + o.w], base[(size_t)(cb+3)*HW + o.w]);
        }
        const float r0 = wv.x*v0.x + wv.y*v1.x + wv.z*v2.x + wv.w*v3.x;
        const float r1 = wv.x*v0.y + wv.y*v1.y + wv.z*v2.y + wv.w*v3.y;
        const float r2 = wv.x*v0.z + wv.y*v1.z + wv.z*v2.z + wv.w*v3.z;
        const float r3 = wv.x*v0.w + wv.y*v1.w + wv.z*v2.w + wv.w*v3.w;
        mx0 = fmaxf(mx0, r0); mx1 = fmaxf(mx1, r1);
        mx2 = fmaxf(mx2, r2); mx3 = fmaxf(mx3, r3);
    }
    const int ob = ((n * C_CH + cb) * H_IMG + h) * W_IMG + w;
    out[ob]          = mx0;
    out[ob + HW]     = mx1;
    out[ob + 2*HW]   = mx2;
    out[ob + 3*HW]   = mx3;
}

extern "C" void kernel_launch(void* const* d_in, const int* in_sizes, int n_in,
                              void* d_out, int out_size, void* d_ws, size_t ws_size,
                              hipStream_t stream) {
    const float* feat2 = (const float*)d_in[1];
    const float* P1    = (const float*)d_in[2];
    const float* P2    = (const float*)d_in[3];
    float* out = (float*)d_out;

    const size_t ft_bytes = (size_t)N_BATCH * C_CH * HW * sizeof(float);
    const bool use_t = (ws_size >= ft_bytes + 256);

    double* Fm = use_t ? (double*)((char*)d_ws + ft_bytes) : (double*)d_ws;
    compute_F_kernel<<<1, 64, 0, stream>>>(P1, P2, Fm);

    if (use_t) {
        float* ft = (float*)d_ws;
        dim3 tb(32, 8);
        dim3 tg(HW / 32, C_CH / 32, N_BATCH);
        transpose_kernel<<<tg, tb, 0, stream>>>(feat2, ft);
        sample_max_kernel<true><<<N_BATCH * HW, 64, 0, stream>>>(ft, Fm, out);
    } else {
        sample_max_kernel<false><<<N_BATCH * HW, 64, 0, stream>>>(feat2, Fm, out);
    }
}

// Round 2
// 139.547 us; speedup vs baseline: 1.0226x; 1.0226x over previous
//
#include <hip/hip_runtime.h>
#include <math.h>

#define N_BATCH 2
#define C_CH    256
#define H_IMG   64
#define W_IMG   64
#define S_SAMP  64
#define HW      (H_IMG * W_IMG)
#define PPB     16   // pixels per block in the bf16 sample kernel

// det of 3x3 with columns u, v, w
__device__ __forceinline__ double det3(const double* u, const double* v, const double* w) {
    return u[0] * (v[1] * w[2] - v[2] * w[1])
         - v[0] * (u[1] * w[2] - u[2] * w[1])
         + w[0] * (u[1] * v[2] - u[2] * v[1]);
}

// Compute fundamental matrix F = skew(P2 @ Cc) @ P2 @ pinv(P1) per batch, fp64.
// Cc = unit-norm null vector of P1 (== eigh smallest eigenvector up to sign; sign
// cancels downstream). pinv(P1) = P1^T (P1 P1^T)^{-1} (full row rank).
__global__ void compute_F_kernel(const float* __restrict__ P1g,
                                 const float* __restrict__ P2g,
                                 double* __restrict__ Fout) {
    int n = threadIdx.x;
    if (n >= N_BATCH) return;
    double p1[3][4], p2[3][4];
    for (int i = 0; i < 3; i++)
        for (int j = 0; j < 4; j++) {
            p1[i][j] = (double)P1g[n * 12 + i * 4 + j];
            p2[i][j] = (double)P2g[n * 12 + i * 4 + j];
        }
    double col[4][3];
    for (int j = 0; j < 4; j++)
        for (int i = 0; i < 3; i++) col[j][i] = p1[i][j];
    const int idx[4][3] = {{1,2,3},{0,2,3},{0,1,3},{0,1,2}};
    double v[4];
    double sgn = 1.0;
    for (int j = 0; j < 4; j++) {
        v[j] = sgn * det3(col[idx[j][0]], col[idx[j][1]], col[idx[j][2]]);
        sgn = -sgn;
    }
    double nrm = sqrt(v[0]*v[0] + v[1]*v[1] + v[2]*v[2] + v[3]*v[3]);
    for (int j = 0; j < 4; j++) v[j] /= nrm;
    double e2[3];
    for (int i = 0; i < 3; i++)
        e2[i] = p2[i][0]*v[0] + p2[i][1]*v[1] + p2[i][2]*v[2] + p2[i][3]*v[3];
    double A[3][3];
    for (int i = 0; i < 3; i++)
        for (int k = 0; k < 3; k++) {
            double s = 0.0;
            for (int j = 0; j < 4; j++) s += p1[i][j] * p1[k][j];
            A[i][k] = s;
        }
    double det = A[0][0]*(A[1][1]*A[2][2] - A[1][2]*A[2][1])
               - A[0][1]*(A[1][0]*A[2][2] - A[1][2]*A[2][0])
               + A[0][2]*(A[1][0]*A[2][1] - A[1][1]*A[2][0]);
    double Ai[3][3];
    Ai[0][0] =  (A[1][1]*A[2][2] - A[1][2]*A[2][1]) / det;
    Ai[0][1] = -(A[0][1]*A[2][2] - A[0][2]*A[2][1]) / det;
    Ai[0][2] =  (A[0][1]*A[1][2] - A[0][2]*A[1][1]) / det;
    Ai[1][0] = -(A[1][0]*A[2][2] - A[1][2]*A[2][0]) / det;
    Ai[1][1] =  (A[0][0]*A[2][2] - A[0][2]*A[2][0]) / det;
    Ai[1][2] = -(A[0][0]*A[1][2] - A[0][2]*A[1][0]) / det;
    Ai[2][0] =  (A[1][0]*A[2][1] - A[1][1]*A[2][0]) / det;
    Ai[2][1] = -(A[0][0]*A[2][1] - A[0][1]*A[2][0]) / det;
    Ai[2][2] =  (A[0][0]*A[1][1] - A[0][1]*A[1][0]) / det;
    double B[3][3];
    for (int i = 0; i < 3; i++)
        for (int m = 0; m < 3; m++) {
            double s = 0.0;
            for (int k = 0; k < 4; k++) s += p2[i][k] * p1[m][k];
            B[i][m] = s;
        }
    double G[3][3];
    for (int i = 0; i < 3; i++)
        for (int j = 0; j < 3; j++)
            G[i][j] = B[i][0]*Ai[0][j] + B[i][1]*Ai[1][j] + B[i][2]*Ai[2][j];
    double F[3][3];
    for (int j = 0; j < 3; j++) {
        F[0][j] = -e2[2]*G[1][j] + e2[1]*G[2][j];
        F[1][j] =  e2[2]*G[0][j] - e2[0]*G[2][j];
        F[2][j] = -e2[1]*G[0][j] + e2[0]*G[1][j];
    }
    for (int i = 0; i < 3; i++)
        for (int j = 0; j < 3; j++) Fout[n * 9 + i * 3 + j] = F[i][j];
}

__device__ __forceinline__ unsigned short f2bf_rne(float x) {
    union { float f; unsigned u; } v; v.f = x;
    unsigned r = v.u + 0x7fffu + ((v.u >> 16) & 1u);
    return (unsigned short)(r >> 16);
}

// (N,C,H,W) fp32 -> (N,H*W,C) bf16: channels contiguous, half the gather bytes
__global__ void transpose_bf16_kernel(const float* __restrict__ in,
                                      unsigned short* __restrict__ outp) {
    __shared__ float tile[32][33];
    const int n  = blockIdx.z;
    const int p0 = blockIdx.x * 32;
    const int c0 = blockIdx.y * 32;
    for (int i = threadIdx.y; i < 32; i += 8)
        tile[i][threadIdx.x] = in[((size_t)n * C_CH + c0 + i) * HW + p0 + threadIdx.x];
    __syncthreads();
    for (int i = threadIdx.y; i < 32; i += 8)
        outp[((size_t)n * HW + p0 + i) * C_CH + c0 + threadIdx.x] =
            f2bf_rne(tile[threadIdx.x][i]);
}

__device__ __forceinline__ void bf4_unpack(uint2 u, float& f0, float& f1, float& f2, float& f3) {
    union { unsigned u; float f; } t;
    t.u = u.x << 16;          f0 = t.f;
    t.u = u.x & 0xffff0000u;  f1 = t.f;
    t.u = u.y << 16;          f2 = t.f;
    t.u = u.y & 0xffff0000u;  f3 = t.f;
}

// Block = 16 consecutive pixels (one row segment), 16 waves, 1 wave per pixel.
// Lane s precomputes tap byte-offsets/weights for sample s into LDS; then each
// lane owns 4 channels and maxes the bilinear result over the 64 samples.
// Results staged in LDS, then written with full 64B-line coalescing.
__global__ __launch_bounds__(1024, 8) void sample_max_bf16_kernel(
    const unsigned short* __restrict__ feat,
    const double* __restrict__ Fm,
    float* __restrict__ out) {
    const int bid    = blockIdx.x;        // [0, 512)
    const int n      = bid >> 8;          // 256 blocks per batch
    const int p_base = (bid & 255) << 4;  // 16-pixel group, within one row
    const int h      = p_base >> 6;
    const int w0     = p_base & 63;
    const int tid    = threadIdx.x;
    const int wid    = tid >> 6;          // wave id == local pixel id
    const int lane   = tid & 63;

    __shared__ int4   s_off[PPB][S_SAMP];
    __shared__ float4 s_wt [PPB][S_SAMP];
    __shared__ float  s_res[PPB][C_CH + 1];

    // ---- per-pixel setup (fp64, matches np reference through the branchy logic) ----
    {
        const int w = w0 + wid;
        const double* F = Fm + n * 9;
        const double wd = (double)w, hd = (double)h;
        const double a = F[0]*wd + F[1]*hd + F[2];
        const double b = F[3]*wd + F[4]*hd + F[5];
        const double c = F[6]*wd + F[7]*hd + F[8];
        const double EPSd = 0.001;
        const double xmaxv = 63.0, ymaxv = 63.0;
        const double sb = (b > 0.0) ? 1.0 : ((b < 0.0) ? -1.0 : 0.0);
        const double sa = (a > 0.0) ? 1.0 : ((a < 0.0) ? -1.0 : 0.0);
        const double db = sb * fmax(fabs(b), EPSd);
        const double da = sa * fmax(fabs(a), EPSd);
        const double by1 = -c / db;
        const double by2 = -(xmaxv * a + c) / db;
        const double bx0 = -c / da;
        const double bx3 = -(ymaxv * b + c) / da;
        const double PX[4] = {bx0, 0.0, xmaxv, bx3};
        const double PY[4] = {0.0, by1, by2, ymaxv};
        bool m[4];
        m[0] = (bx0 >= EPSd) && (bx0 <  xmaxv - EPSd);
        m[1] = (by1 >  EPSd) && (by1 <= ymaxv - EPSd);
        m[2] = (by2 >= EPSd) && (by2 <  ymaxv - EPSd);
        m[3] = (bx3 >  EPSd) && (bx3 <= xmaxv - EPSd);
        const int nint = (int)m[0] + (int)m[1] + (int)m[2] + (int)m[3];
        const bool valid2 = (nint >= 2);
        bool tm[4];
        if (valid2) { tm[0]=m[0]; tm[1]=m[1]; tm[2]=m[2]; tm[3]=m[3]; }
        else        { tm[0]=true; tm[1]=true; tm[2]=false; tm[3]=false; }
        int i0 = -1, i1 = -1;
        for (int i = 0; i < 4; i++) if (tm[i])  { if (i0 < 0) i0 = i; else if (i1 < 0) i1 = i; }
        for (int i = 0; i < 4; i++) if (!tm[i]) { if (i0 < 0) i0 = i; else if (i1 < 0) i1 = i; }
        double sx, sy, vx, vy;
        if (valid2) { sx = PX[i0]; sy = PY[i0]; vx = PX[i1] - sx; vy = PY[i1] - sy; }
        else        { sx = -10000.0; sy = -10000.0; vx = 0.0; vy = 0.0; }

        // lane == sample index s
        const double t  = (double)lane / 63.0;
        const double lx = sx + vx * t;
        const double ly = sy + vy * t;
        const double gx = lx / 63.0 * 2.0 - 1.0;
        const double gy = ly / 63.0 * 2.0 - 1.0;
        const double x  = (gx + 1.0) * 32.0 - 0.5;
        const double y  = (gy + 1.0) * 32.0 - 0.5;
        const double x0 = floor(x), y0 = floor(y);
        const double wx = x - x0,  wy = y - y0;
        const double wt4[4] = {(1.0-wx)*(1.0-wy), wx*(1.0-wy), (1.0-wx)*wy, wx*wy};
        int   offs[4];
        float wts[4];
        #pragma unroll
        for (int k = 0; k < 4; k++) {
            const double ix = x0 + (double)(k & 1);
            const double iy = y0 + (double)(k >> 1);
            const bool val = (ix >= 0.0) && (ix < 64.0) && (iy >= 0.0) && (iy < 64.0);
            const double ixc = fmin(fmax(ix, 0.0), 63.0);
            const double iyc = fmin(fmax(iy, 0.0), 63.0);
            // byte offset into (HW, C) bf16 plane: pixel * 256ch * 2B
            offs[k] = (((int)iyc) * 64 + (int)ixc) * (C_CH * 2);
            wts[k]  = val ? (float)wt4[k] : 0.0f;
        }
        s_off[wid][lane] = make_int4(offs[0], offs[1], offs[2], offs[3]);
        s_wt [wid][lane] = make_float4(wts[0], wts[1], wts[2], wts[3]);
    }
    __syncthreads();

    // ---- gather + bilinear + max over samples ----
    const char* base = (const char*)(feat + (size_t)n * HW * C_CH) + lane * 8; // 4 ch * 2B
    float mx0 = -INFINITY, mx1 = -INFINITY, mx2 = -INFINITY, mx3 = -INFINITY;
    #pragma unroll 4
    for (int s = 0; s < S_SAMP; s++) {
        const int4   o  = s_off[wid][s];
        const float4 wv = s_wt[wid][s];
        const uint2 ua = *(const uint2*)(base + o.x);
        const uint2 ub = *(const uint2*)(base + o.y);
        const uint2 uc = *(const uint2*)(base + o.z);
        const uint2 ud = *(const uint2*)(base + o.w);
        float a0,a1,a2,a3, b0,b1,b2,b3, c0,c1,c2,c3, d0,d1,d2,d3;
        bf4_unpack(ua, a0,a1,a2,a3);
        bf4_unpack(ub, b0,b1,b2,b3);
        bf4_unpack(uc, c0,c1,c2,c3);
        bf4_unpack(ud, d0,d1,d2,d3);
        const float r0 = wv.x*a0 + wv.y*b0 + wv.z*c0 + wv.w*d0;
        const float r1 = wv.x*a1 + wv.y*b1 + wv.z*c1 + wv.w*d1;
        const float r2 = wv.x*a2 + wv.y*b2 + wv.z*c2 + wv.w*d2;
        const float r3 = wv.x*a3 + wv.y*b3 + wv.z*c3 + wv.w*d3;
        mx0 = fmaxf(mx0, r0); mx1 = fmaxf(mx1, r1);
        mx2 = fmaxf(mx2, r2); mx3 = fmaxf(mx3, r3);
    }

    // ---- stage results, then coalesced write (full 64B lines per wave) ----
    {
        const int cb = lane * 4;
        s_res[wid][cb + 0] = mx0;
        s_res[wid][cb + 1] = mx1;
        s_res[wid][cb + 2] = mx2;
        s_res[wid][cb + 3] = mx3;
    }
    __syncthreads();
    {
        const int j  = tid & 15;   // pixel within group
        const int c0 = tid >> 4;   // 0..63
        const size_t obase = (size_t)n * C_CH * HW + h * 64 + w0 + j;
        #pragma unroll
        for (int k = 0; k < 4; k++) {
            const int c = c0 + (k << 6);
            out[obase + (size_t)c * HW] = s_res[j][c];
        }
    }
}

// Fallback (no workspace): direct fp32 gather from (N,C,H,W), 1 wave per pixel.
__global__ __launch_bounds__(64) void sample_max_fallback_kernel(
    const float* __restrict__ feat, const double* __restrict__ Fm,
    float* __restrict__ out) {
    const int bid  = blockIdx.x;
    const int n    = bid >> 12;
    const int p    = bid & 4095;
    const int h    = p >> 6;
    const int w    = p & 63;
    const int lane = threadIdx.x;
    __shared__ int4   s_off[S_SAMP];
    __shared__ float4 s_wt[S_SAMP];
    {
        const double* F = Fm + n * 9;
        const double wd = (double)w, hd = (double)h;
        const double a = F[0]*wd + F[1]*hd + F[2];
        const double b = F[3]*wd + F[4]*hd + F[5];
        const double c = F[6]*wd + F[7]*hd + F[8];
        const double EPSd = 0.001;
        const double xmaxv = 63.0, ymaxv = 63.0;
        const double sb = (b > 0.0) ? 1.0 : ((b < 0.0) ? -1.0 : 0.0);
        const double sa = (a > 0.0) ? 1.0 : ((a < 0.0) ? -1.0 : 0.0);
        const double db = sb * fmax(fabs(b), EPSd);
        const double da = sa * fmax(fabs(a), EPSd);
        const double by1 = -c / db;
        const double by2 = -(xmaxv * a + c) / db;
        const double bx0 = -c / da;
        const double bx3 = -(ymaxv * b + c) / da;
        const double PX[4] = {bx0, 0.0, xmaxv, bx3};
        const double PY[4] = {0.0, by1, by2, ymaxv};
        bool m[4];
        m[0] = (bx0 >= EPSd) && (bx0 <  xmaxv - EPSd);
        m[1] = (by1 >  EPSd) && (by1 <= ymaxv - EPSd);
        m[2] = (by2 >= EPSd) && (by2 <  ymaxv - EPSd);
        m[3] = (bx3 >  EPSd) && (bx3 <= xmaxv - EPSd);
        const int nint = (int)m[0] + (int)m[1] + (int)m[2] + (int)m[3];
        const bool valid2 = (nint >= 2);
        bool tm[4];
        if (valid2) { tm[0]=m[0]; tm[1]=m[1]; tm[2]=m[2]; tm[3]=m[3]; }
        else        { tm[0]=true; tm[1]=true; tm[2]=false; tm[3]=false; }
        int i0 = -1, i1 = -1;
        for (int i = 0; i < 4; i++) if (tm[i])  { if (i0 < 0) i0 = i; else if (i1 < 0) i1 = i; }
        for (int i = 0; i < 4; i++) if (!tm[i]) { if (i0 < 0) i0 = i; else if (i1 < 0) i1 = i; }
        double sx, sy, vx, vy;
        if (valid2) { sx = PX[i0]; sy = PY[i0]; vx = PX[i1] - sx; vy = PY[i1] - sy; }
        else        { sx = -10000.0; sy = -10000.0; vx = 0.0; vy = 0.0; }
        const double t  = (double)lane / 63.0;
        const double lx = sx + vx * t;
        const double ly = sy + vy * t;
        const double gx = lx / 63.0 * 2.0 - 1.0;
        const double gy = ly / 63.0 * 2.0 - 1.0;
        const double x  = (gx + 1.0) * 32.0 - 0.5;
        const double y  = (gy + 1.0) * 32.0 - 0.5;
        const double x0 = floor(x), y0 = floor(y);
        const double wx = x - x0,  wy = y - y0;
        const double wt4[4] = {(1.0-wx)*(1.0-wy), wx*(1.0-wy), (1.0-wx)*wy, wx*wy};
        int   offs[4];
        float wts[4];
        #pragma unroll
        for (int k = 0; k < 4; k++) {
            const double ix = x0 + (double)(k & 1);
            const double iy = y0 + (double)(k >> 1);
            const bool val = (ix >= 0.0) && (ix < 64.0) && (iy >= 0.0) && (iy < 64.0);
            const double ixc = fmin(fmax(ix, 0.0), 63.0);
            const double iyc = fmin(fmax(iy, 0.0), 63.0);
            offs[k] = ((int)iyc) * 64 + (int)ixc;
            wts[k]  = val ? (float)wt4[k] : 0.0f;
        }
        s_off[lane] = make_int4(offs[0], offs[1], offs[2], offs[3]);
        s_wt[lane]  = make_float4(wts[0], wts[1], wts[2], wts[3]);
    }
    __syncthreads();
    const float* base = feat + (size_t)n * (size_t)HW * C_CH;
    float mx0 = -INFINITY, mx1 = -INFINITY, mx2 = -INFINITY, mx3 = -INFINITY;
    const int cb = lane * 4;
    for (int s = 0; s < S_SAMP; s++) {
        const int4   o  = s_off[s];
        const float4 wv = s_wt[s];
        float4 v0 = make_float4(base[(size_t)(cb+0)*HW + o.x], base[(size_t)(cb+1)*HW + o.x],
                                base[(size_t)(cb+2)*HW + o.x], base[(size_t)(cb+3)*HW + o.x]);
        float4 v1 = make_float4(base[(size_t)(cb+0)*HW + o.y], base[(size_t)(cb+1)*HW + o.y],
                                base[(size_t)(cb+2)*HW + o.y], base[(size_t)(cb+3)*HW + o.y]);
        float4 v2 = make_float4(base[(size_t)(cb+0)*HW + o.z], base[(size_t)(cb+1)*HW + o.z],
                                base[(size_t)(cb+2)*HW + o.z], base[(size_t)(cb+3)*HW + o.z]);
        float4 v3 = make_float4(base[(size_t)(cb+0)*HW + o.w], base[(size_t)(cb+1)*HW + o.w],
                                base[(size_t)(cb+2)*HW + o.w], base[(size_t)(cb+3)*HW + o.w]);
        mx0 = fmaxf(mx0, wv.x*v0.x + wv.y*v1.x + wv.z*v2.x + wv.w*v3.x);
        mx1 = fmaxf(mx1, wv.x*v0.y + wv.y*v1.y + wv.z*v2.y + wv.w*v3.y);
        mx2 = fmaxf(mx2, wv.x*v0.z + wv.y*v1.z + wv.z*v2.z + wv.w*v3.z);
        mx3 = fmaxf(mx3, wv.x*v0.w + wv.y*v1.w + wv.z*v2.w + wv.w*v3.w);
    }
    const int ob = ((n * C_CH + cb) * H_IMG + h) * W_IMG + w;
    out[ob]        = mx0;
    out[ob + HW]   = mx1;
    out[ob + 2*HW] = mx2;
    out[ob + 3*HW] = mx3;
}

extern "C" void kernel_launch(void* const* d_in, const int* in_sizes, int n_in,
                              void* d_out, int out_size, void* d_ws, size_t ws_size,
                              hipStream_t stream) {
    const float* feat2 = (const float*)d_in[1];
    const float* P1    = (const float*)d_in[2];
    const float* P2    = (const float*)d_in[3];
    float* out = (float*)d_out;

    const size_t ft_bytes = (size_t)N_BATCH * HW * C_CH * sizeof(unsigned short); // 4 MB
    const bool use_t = (ws_size >= ft_bytes + 256);

    double* Fm = use_t ? (double*)((char*)d_ws + ft_bytes) : (double*)d_ws;
    compute_F_kernel<<<1, 64, 0, stream>>>(P1, P2, Fm);

    if (use_t) {
        unsigned short* ft = (unsigned short*)d_ws;
        dim3 tb(32, 8);
        dim3 tg(HW / 32, C_CH / 32, N_BATCH);
        transpose_bf16_kernel<<<tg, tb, 0, stream>>>(feat2, ft);
        sample_max_bf16_kernel<<<(N_BATCH * HW) / PPB, 1024, 0, stream>>>(ft, Fm, out);
    } else {
        sample_max_fallback_kernel<<<N_BATCH * HW, 64, 0, stream>>>(feat2, Fm, out);
    }
}

// Round 3
// 137.849 us; speedup vs baseline: 1.0352x; 1.0123x over previous
//
#include <hip/hip_runtime.h>
#include <math.h>

#define N_BATCH 2
#define C_CH    256
#define H_IMG   64
#define W_IMG   64
#define S_SAMP  64
#define HW      (H_IMG * W_IMG)
#define PPB     8    // pixels per block in the sample kernel

// det of 3x3 with columns u, v, w
__device__ __forceinline__ double det3(const double* u, const double* v, const double* w) {
    return u[0] * (v[1] * w[2] - v[2] * w[1])
         - v[0] * (u[1] * w[2] - u[2] * w[1])
         + w[0] * (u[1] * v[2] - u[2] * v[1]);
}

// F = skew(P2 @ Cc) @ P2 @ pinv(P1), fp64. Cc = unit null vector of P1 (== eigh
// smallest eigenvector up to sign; sign cancels downstream). pinv via P1^T (P1 P1^T)^-1.
__device__ void compute_F_one(const float* __restrict__ P1g,
                              const float* __restrict__ P2g,
                              int n, double* __restrict__ Fout) {
    double p1[3][4], p2[3][4];
    for (int i = 0; i < 3; i++)
        for (int j = 0; j < 4; j++) {
            p1[i][j] = (double)P1g[n * 12 + i * 4 + j];
            p2[i][j] = (double)P2g[n * 12 + i * 4 + j];
        }
    double col[4][3];
    for (int j = 0; j < 4; j++)
        for (int i = 0; i < 3; i++) col[j][i] = p1[i][j];
    const int idx[4][3] = {{1,2,3},{0,2,3},{0,1,3},{0,1,2}};
    double v[4];
    double sgn = 1.0;
    for (int j = 0; j < 4; j++) {
        v[j] = sgn * det3(col[idx[j][0]], col[idx[j][1]], col[idx[j][2]]);
        sgn = -sgn;
    }
    double nrm = sqrt(v[0]*v[0] + v[1]*v[1] + v[2]*v[2] + v[3]*v[3]);
    for (int j = 0; j < 4; j++) v[j] /= nrm;
    double e2[3];
    for (int i = 0; i < 3; i++)
        e2[i] = p2[i][0]*v[0] + p2[i][1]*v[1] + p2[i][2]*v[2] + p2[i][3]*v[3];
    double A[3][3];
    for (int i = 0; i < 3; i++)
        for (int k = 0; k < 3; k++) {
            double s = 0.0;
            for (int j = 0; j < 4; j++) s += p1[i][j] * p1[k][j];
            A[i][k] = s;
        }
    double det = A[0][0]*(A[1][1]*A[2][2] - A[1][2]*A[2][1])
               - A[0][1]*(A[1][0]*A[2][2] - A[1][2]*A[2][0])
               + A[0][2]*(A[1][0]*A[2][1] - A[1][1]*A[2][0]);
    double Ai[3][3];
    Ai[0][0] =  (A[1][1]*A[2][2] - A[1][2]*A[2][1]) / det;
    Ai[0][1] = -(A[0][1]*A[2][2] - A[0][2]*A[2][1]) / det;
    Ai[0][2] =  (A[0][1]*A[1][2] - A[0][2]*A[1][1]) / det;
    Ai[1][0] = -(A[1][0]*A[2][2] - A[1][2]*A[2][0]) / det;
    Ai[1][1] =  (A[0][0]*A[2][2] - A[0][2]*A[2][0]) / det;
    Ai[1][2] = -(A[0][0]*A[1][2] - A[0][2]*A[1][0]) / det;
    Ai[2][0] =  (A[1][0]*A[2][1] - A[1][1]*A[2][0]) / det;
    Ai[2][1] = -(A[0][0]*A[2][1] - A[0][1]*A[2][0]) / det;
    Ai[2][2] =  (A[0][0]*A[1][1] - A[0][1]*A[1][0]) / det;
    double B[3][3];
    for (int i = 0; i < 3; i++)
        for (int m = 0; m < 3; m++) {
            double s = 0.0;
            for (int k = 0; k < 4; k++) s += p2[i][k] * p1[m][k];
            B[i][m] = s;
        }
    double G[3][3];
    for (int i = 0; i < 3; i++)
        for (int j = 0; j < 3; j++)
            G[i][j] = B[i][0]*Ai[0][j] + B[i][1]*Ai[1][j] + B[i][2]*Ai[2][j];
    double F[3][3];
    for (int j = 0; j < 3; j++) {
        F[0][j] = -e2[2]*G[1][j] + e2[1]*G[2][j];
        F[1][j] =  e2[2]*G[0][j] - e2[0]*G[2][j];
        F[2][j] = -e2[1]*G[0][j] + e2[0]*G[1][j];
    }
    for (int i = 0; i < 3; i++)
        for (int j = 0; j < 3; j++) Fout[n * 9 + i * 3 + j] = F[i][j];
}

__device__ __forceinline__ unsigned f2bf_rne_u(float x) {
    union { float f; unsigned u; } v; v.f = x;
    return (v.u + 0x7fffu + ((v.u >> 16) & 1u)) >> 16;
}

// Fused: (N,C,H,W) fp32 -> (N,H*W,C) bf16 transpose; block 0 also computes F.
__global__ void transpose_F_kernel(const float* __restrict__ in,
                                   unsigned short* __restrict__ outp,
                                   const float* __restrict__ P1,
                                   const float* __restrict__ P2,
                                   double* __restrict__ Fout) {
    __shared__ float tile[32][33];
    const int n  = blockIdx.z;
    const int p0 = blockIdx.x * 32;
    const int c0 = blockIdx.y * 32;
    const int tx = threadIdx.x, ty = threadIdx.y;

    if (blockIdx.x == 0 && blockIdx.y == 0 && blockIdx.z == 0) {
        const int t = ty * 32 + tx;
        if (t < N_BATCH) compute_F_one(P1, P2, t, Fout);
    }

    for (int i = ty; i < 32; i += 8)
        tile[i][tx] = in[((size_t)n * C_CH + c0 + i) * HW + p0 + tx];
    __syncthreads();

    // write packed pairs of bf16 (uint) — 64B bursts per 16 consecutive threads
    const int t = ty * 32 + tx;
    unsigned* outw = (unsigned*)(outp + ((size_t)n * HW + p0) * C_CH + c0);
    #pragma unroll
    for (int r = 0; r < 2; r++) {
        const int u  = t + r * 256;     // uint index in [0,512)
        const int i  = u >> 4;          // pixel within tile
        const int cp = u & 15;          // channel pair
        const unsigned lo = f2bf_rne_u(tile[2 * cp][i]);
        const unsigned hi = f2bf_rne_u(tile[2 * cp + 1][i]);
        outw[(size_t)i * (C_CH / 2) + cp] = lo | (hi << 16);
    }
}

__device__ __forceinline__ void bf4_unpack(uint2 u, float& f0, float& f1, float& f2, float& f3) {
    union { unsigned u; float f; } t;
    t.u = u.x << 16;          f0 = t.f;
    t.u = u.x & 0xffff0000u;  f1 = t.f;
    t.u = u.y << 16;          f2 = t.f;
    t.u = u.y & 0xffff0000u;  f3 = t.f;
}

// Block = 8 consecutive pixels in one row, 8 waves, 1 wave per pixel.
// Lane s precomputes tap byte-offsets/weights for sample s into LDS; then each
// lane owns 4 channels and maxes the bilinear result over the 64 samples.
__global__ __launch_bounds__(512, 8) void sample_max_bf16_kernel(
    const unsigned short* __restrict__ feat,
    const double* __restrict__ Fm,
    float* __restrict__ out) {
    const int bid    = blockIdx.x;        // [0, 1024)
    const int n      = bid >> 9;          // 512 blocks per batch
    const int p_base = (bid & 511) << 3;  // 8-pixel group within one row
    const int h      = p_base >> 6;
    const int w0     = p_base & 63;
    const int tid    = threadIdx.x;
    const int wid    = tid >> 6;          // wave id == local pixel id
    const int lane   = tid & 63;

    __shared__ int4   s_off[PPB][S_SAMP];
    __shared__ float4 s_wt [PPB][S_SAMP];
    __shared__ float  s_res[PPB][C_CH + 1];

    // ---- per-pixel setup (fp64, matches np reference through the branchy logic) ----
    {
        const int w = w0 + wid;
        const double* F = Fm + n * 9;
        const double wd = (double)w, hd = (double)h;
        const double a = F[0]*wd + F[1]*hd + F[2];
        const double b = F[3]*wd + F[4]*hd + F[5];
        const double c = F[6]*wd + F[7]*hd + F[8];
        const double EPSd = 0.001;
        const double xmaxv = 63.0, ymaxv = 63.0;
        const double sb = (b > 0.0) ? 1.0 : ((b < 0.0) ? -1.0 : 0.0);
        const double sa = (a > 0.0) ? 1.0 : ((a < 0.0) ? -1.0 : 0.0);
        const double db = sb * fmax(fabs(b), EPSd);
        const double da = sa * fmax(fabs(a), EPSd);
        const double by1 = -c / db;
        const double by2 = -(xmaxv * a + c) / db;
        const double bx0 = -c / da;
        const double bx3 = -(ymaxv * b + c) / da;
        const double PX[4] = {bx0, 0.0, xmaxv, bx3};
        const double PY[4] = {0.0, by1, by2, ymaxv};
        bool m[4];
        m[0] = (bx0 >= EPSd) && (bx0 <  xmaxv - EPSd);
        m[1] = (by1 >  EPSd) && (by1 <= ymaxv - EPSd);
        m[2] = (by2 >= EPSd) && (by2 <  ymaxv - EPSd);
        m[3] = (bx3 >  EPSd) && (bx3 <= xmaxv - EPSd);
        const int nint = (int)m[0] + (int)m[1] + (int)m[2] + (int)m[3];
        const bool valid2 = (nint >= 2);
        bool tm[4];
        if (valid2) { tm[0]=m[0]; tm[1]=m[1]; tm[2]=m[2]; tm[3]=m[3]; }
        else        { tm[0]=true; tm[1]=true; tm[2]=false; tm[3]=false; }
        int i0 = -1, i1 = -1;
        for (int i = 0; i < 4; i++) if (tm[i])  { if (i0 < 0) i0 = i; else if (i1 < 0) i1 = i; }
        for (int i = 0; i < 4; i++) if (!tm[i]) { if (i0 < 0) i0 = i; else if (i1 < 0) i1 = i; }
        double sx, sy, vx, vy;
        if (valid2) { sx = PX[i0]; sy = PY[i0]; vx = PX[i1] - sx; vy = PY[i1] - sy; }
        else        { sx = -10000.0; sy = -10000.0; vx = 0.0; vy = 0.0; }

        // lane == sample index s
        const double t  = (double)lane / 63.0;
        const double lx = sx + vx * t;
        const double ly = sy + vy * t;
        const double gx = lx / 63.0 * 2.0 - 1.0;
        const double gy = ly / 63.0 * 2.0 - 1.0;
        const double x  = (gx + 1.0) * 32.0 - 0.5;
        const double y  = (gy + 1.0) * 32.0 - 0.5;
        const double x0 = floor(x), y0 = floor(y);
        const double wx = x - x0,  wy = y - y0;
        const double wt4[4] = {(1.0-wx)*(1.0-wy), wx*(1.0-wy), (1.0-wx)*wy, wx*wy};
        int   offs[4];
        float wts[4];
        #pragma unroll
        for (int k = 0; k < 4; k++) {
            const double ix = x0 + (double)(k & 1);
            const double iy = y0 + (double)(k >> 1);
            const bool val = (ix >= 0.0) && (ix < 64.0) && (iy >= 0.0) && (iy < 64.0);
            const double ixc = fmin(fmax(ix, 0.0), 63.0);
            const double iyc = fmin(fmax(iy, 0.0), 63.0);
            offs[k] = (((int)iyc) * 64 + (int)ixc) * (C_CH * 2);  // byte offset, NHWC bf16
            wts[k]  = val ? (float)wt4[k] : 0.0f;
        }
        s_off[wid][lane] = make_int4(offs[0], offs[1], offs[2], offs[3]);
        s_wt [wid][lane] = make_float4(wts[0], wts[1], wts[2], wts[3]);
    }
    __syncthreads();

    // ---- gather + bilinear + max over samples ----
    const char* base = (const char*)(feat + (size_t)n * HW * C_CH) + lane * 8; // 4 ch * 2B
    float mx0 = -INFINITY, mx1 = -INFINITY, mx2 = -INFINITY, mx3 = -INFINITY;
    #pragma unroll 4
    for (int s = 0; s < S_SAMP; s++) {
        const int4   o  = s_off[wid][s];
        const float4 wv = s_wt[wid][s];
        const uint2 ua = *(const uint2*)(base + o.x);
        const uint2 ub = *(const uint2*)(base + o.y);
        const uint2 uc = *(const uint2*)(base + o.z);
        const uint2 ud = *(const uint2*)(base + o.w);
        float a0,a1,a2,a3, b0,b1,b2,b3, c0,c1,c2,c3, d0,d1,d2,d3;
        bf4_unpack(ua, a0,a1,a2,a3);
        bf4_unpack(ub, b0,b1,b2,b3);
        bf4_unpack(uc, c0,c1,c2,c3);
        bf4_unpack(ud, d0,d1,d2,d3);
        const float r0 = wv.x*a0 + wv.y*b0 + wv.z*c0 + wv.w*d0;
        const float r1 = wv.x*a1 + wv.y*b1 + wv.z*c1 + wv.w*d1;
        const float r2 = wv.x*a2 + wv.y*b2 + wv.z*c2 + wv.w*d2;
        const float r3 = wv.x*a3 + wv.y*b3 + wv.z*c3 + wv.w*d3;
        mx0 = fmaxf(mx0, r0); mx1 = fmaxf(mx1, r1);
        mx2 = fmaxf(mx2, r2); mx3 = fmaxf(mx3, r3);
    }

    // ---- stage results, then write out (32B bursts; 8-pixel rows) ----
    {
        const int cb = lane * 4;
        s_res[wid][cb + 0] = mx0;
        s_res[wid][cb + 1] = mx1;
        s_res[wid][cb + 2] = mx2;
        s_res[wid][cb + 3] = mx3;
    }
    __syncthreads();
    {
        const int j  = tid & 7;    // pixel within group
        const int c0 = tid >> 3;   // 0..63
        const size_t obase = (size_t)n * C_CH * HW + h * 64 + w0 + j;
        #pragma unroll
        for (int k = 0; k < 4; k++) {
            const int c = c0 + (k << 6);
            out[obase + (size_t)c * HW] = s_res[j][c];
        }
    }
}

// Fallback (no workspace): direct fp32 gather from (N,C,H,W), 1 wave per pixel.
__global__ __launch_bounds__(64) void sample_max_fallback_kernel(
    const float* __restrict__ feat, const double* __restrict__ Fm,
    float* __restrict__ out) {
    const int bid  = blockIdx.x;
    const int n    = bid >> 12;
    const int p    = bid & 4095;
    const int h    = p >> 6;
    const int w    = p & 63;
    const int lane = threadIdx.x;
    __shared__ int4   s_off[S_SAMP];
    __shared__ float4 s_wt[S_SAMP];
    {
        const double* F = Fm + n * 9;
        const double wd = (double)w, hd = (double)h;
        const double a = F[0]*wd + F[1]*hd + F[2];
        const double b = F[3]*wd + F[4]*hd + F[5];
        const double c = F[6]*wd + F[7]*hd + F[8];
        const double EPSd = 0.001;
        const double xmaxv = 63.0, ymaxv = 63.0;
        const double sb = (b > 0.0) ? 1.0 : ((b < 0.0) ? -1.0 : 0.0);
        const double sa = (a > 0.0) ? 1.0 : ((a < 0.0) ? -1.0 : 0.0);
        const double db = sb * fmax(fabs(b), EPSd);
        const double da = sa * fmax(fabs(a), EPSd);
        const double by1 = -c / db;
        const double by2 = -(xmaxv * a + c) / db;
        const double bx0 = -c / da;
        const double bx3 = -(ymaxv * b + c) / da;
        const double PX[4] = {bx0, 0.0, xmaxv, bx3};
        const double PY[4] = {0.0, by1, by2, ymaxv};
        bool m[4];
        m[0] = (bx0 >= EPSd) && (bx0 <  xmaxv - EPSd);
        m[1] = (by1 >  EPSd) && (by1 <= ymaxv - EPSd);
        m[2] = (by2 >= EPSd) && (by2 <  ymaxv - EPSd);
        m[3] = (bx3 >  EPSd) && (bx3 <= xmaxv - EPSd);
        const int nint = (int)m[0] + (int)m[1] + (int)m[2] + (int)m[3];
        const bool valid2 = (nint >= 2);
        bool tm[4];
        if (valid2) { tm[0]=m[0]; tm[1]=m[1]; tm[2]=m[2]; tm[3]=m[3]; }
        else        { tm[0]=true; tm[1]=true; tm[2]=false; tm[3]=false; }
        int i0 = -1, i1 = -1;
        for (int i = 0; i < 4; i++) if (tm[i])  { if (i0 < 0) i0 = i; else if (i1 < 0) i1 = i; }
        for (int i = 0; i < 4; i++) if (!tm[i]) { if (i0 < 0) i0 = i; else if (i1 < 0) i1 = i; }
        double sx, sy, vx, vy;
        if (valid2) { sx = PX[i0]; sy = PY[i0]; vx = PX[i1] - sx; vy = PY[i1] - sy; }
        else        { sx = -10000.0; sy = -10000.0; vx = 0.0; vy = 0.0; }
        const double t  = (double)lane / 63.0;
        const double lx = sx + vx * t;
        const double ly = sy + vy * t;
        const double gx = lx / 63.0 * 2.0 - 1.0;
        const double gy = ly / 63.0 * 2.0 - 1.0;
        const double x  = (gx + 1.0) * 32.0 - 0.5;
        const double y  = (gy + 1.0) * 32.0 - 0.5;
        const double x0 = floor(x), y0 = floor(y);
        const double wx = x - x0,  wy = y - y0;
        const double wt4[4] = {(1.0-wx)*(1.0-wy), wx*(1.0-wy), (1.0-wx)*wy, wx*wy};
        int   offs[4];
        float wts[4];
        #pragma unroll
        for (int k = 0; k < 4; k++) {
            const double ix = x0 + (double)(k & 1);
            const double iy = y0 + (double)(k >> 1);
            const bool val = (ix >= 0.0) && (ix < 64.0) && (iy >= 0.0) && (iy < 64.0);
            const double ixc = fmin(fmax(ix, 0.0), 63.0);
            const double iyc = fmin(fmax(iy, 0.0), 63.0);
            offs[k] = ((int)iyc) * 64 + (int)ixc;
            wts[k]  = val ? (float)wt4[k] : 0.0f;
        }
        s_off[lane] = make_int4(offs[0], offs[1], offs[2], offs[3]);
        s_wt[lane]  = make_float4(wts[0], wts[1], wts[2], wts[3]);
    }
    __syncthreads();
    const float* base = feat + (size_t)n * (size_t)HW * C_CH;
    float mx0 = -INFINITY, mx1 = -INFINITY, mx2 = -INFINITY, mx3 = -INFINITY;
    const int cb = lane * 4;
    for (int s = 0; s < S_SAMP; s++) {
        const int4   o  = s_off[s];
        const float4 wv = s_wt[s];
        float4 v0 = make_float4(base[(size_t)(cb+0)*HW + o.x], base[(size_t)(cb+1)*HW + o.x],
                                base[(size_t)(cb+2)*HW + o.x], base[(size_t)(cb+3)*HW + o.x]);
        float4 v1 = make_float4(base[(size_t)(cb+0)*HW + o.y], base[(size_t)(cb+1)*HW + o.y],
                                base[(size_t)(cb+2)*HW + o.y], base[(size_t)(cb+3)*HW + o.y]);
        float4 v2 = make_float4(base[(size_t)(cb+0)*HW + o.z], base[(size_t)(cb+1)*HW + o.z],
                                base[(size_t)(cb+2)*HW + o.z], base[(size_t)(cb+3)*HW + o.z]);
        float4 v3 = make_float4(base[(size_t)(cb+0)*HW + o.w], base[(size_t)(cb+1)*HW + o.w],
                                base[(size_t)(cb+2)*HW + o.w], base[(size_t)(cb+3)*HW + o.w]);
        mx0 = fmaxf(mx0, wv.x*v0.x + wv.y*v1.x + wv.z*v2.x + wv.w*v3.x);
        mx1 = fmaxf(mx1, wv.x*v0.y + wv.y*v1.y + wv.z*v2.y + wv.w*v3.y);
        mx2 = fmaxf(mx2, wv.x*v0.z + wv.y*v1.z + wv.z*v2.z + wv.w*v3.z);
        mx3 = fmaxf(mx3, wv.x*v0.w + wv.y*v1.w + wv.z*v2.w + wv.w*v3.w);
    }
    const int ob = ((n * C_CH + cb) * H_IMG + h) * W_IMG + w;
    out[ob]        = mx0;
    out[ob + HW]   = mx1;
    out[ob + 2*HW] = mx2;
    out[ob + 3*HW] = mx3;
}

__global__ void compute_F_only_kernel(const float* __restrict__ P1,
                                      const float* __restrict__ P2,
                                      double* __restrict__ Fout) {
    int n = threadIdx.x;
    if (n < N_BATCH) compute_F_one(P1, P2, n, Fout);
}

extern "C" void kernel_launch(void* const* d_in, const int* in_sizes, int n_in,
                              void* d_out, int out_size, void* d_ws, size_t ws_size,
                              hipStream_t stream) {
    const float* feat2 = (const float*)d_in[1];
    const float* P1    = (const float*)d_in[2];
    const float* P2    = (const float*)d_in[3];
    float* out = (float*)d_out;

    const size_t ft_bytes = (size_t)N_BATCH * HW * C_CH * sizeof(unsigned short); // 4 MB
    const bool use_t = (ws_size >= ft_bytes + 256);

    if (use_t) {
        unsigned short* ft = (unsigned short*)d_ws;
        double* Fm = (double*)((char*)d_ws + ft_bytes);
        dim3 tb(32, 8);
        dim3 tg(HW / 32, C_CH / 32, N_BATCH);
        transpose_F_kernel<<<tg, tb, 0, stream>>>(feat2, ft, P1, P2, Fm);
        sample_max_bf16_kernel<<<(N_BATCH * HW) / PPB, 512, 0, stream>>>(ft, Fm, out);
    } else {
        double* Fm = (double*)d_ws;
        compute_F_only_kernel<<<1, 64, 0, stream>>>(P1, P2, Fm);
        sample_max_fallback_kernel<<<N_BATCH * HW, 64, 0, stream>>>(feat2, Fm, out);
    }
}

// Round 5
// 107.885 us; speedup vs baseline: 1.3227x; 1.2777x over previous
//
#include <hip/hip_runtime.h>
#include <math.h>

#define N_BATCH 2
#define C_CH    256
#define H_IMG   64
#define W_IMG   64
#define S_SAMP  64
#define HW      (H_IMG * W_IMG)
#define PPB     8    // pixels per block in the sample kernel (4 waves, 2 px/wave)

typedef _Float16 h2 __attribute__((ext_vector_type(2)));

// det of 3x3 with columns u, v, w
__device__ __forceinline__ double det3(const double* u, const double* v, const double* w) {
    return u[0] * (v[1] * w[2] - v[2] * w[1])
         - v[0] * (u[1] * w[2] - u[2] * w[1])
         + w[0] * (u[1] * v[2] - u[2] * v[1]);
}

// F = skew(P2 @ Cc) @ P2 @ pinv(P1), fp64. Cc = unit null vector of P1 (== eigh
// smallest eigenvector up to sign; sign cancels downstream). pinv via P1^T (P1 P1^T)^-1.
__device__ void compute_F_one(const float* __restrict__ P1g,
                              const float* __restrict__ P2g,
                              int n, double* __restrict__ Fout) {
    double p1[3][4], p2[3][4];
    for (int i = 0; i < 3; i++)
        for (int j = 0; j < 4; j++) {
            p1[i][j] = (double)P1g[n * 12 + i * 4 + j];
            p2[i][j] = (double)P2g[n * 12 + i * 4 + j];
        }
    double col[4][3];
    for (int j = 0; j < 4; j++)
        for (int i = 0; i < 3; i++) col[j][i] = p1[i][j];
    const int idx[4][3] = {{1,2,3},{0,2,3},{0,1,3},{0,1,2}};
    double v[4];
    double sgn = 1.0;
    for (int j = 0; j < 4; j++) {
        v[j] = sgn * det3(col[idx[j][0]], col[idx[j][1]], col[idx[j][2]]);
        sgn = -sgn;
    }
    double nrm = sqrt(v[0]*v[0] + v[1]*v[1] + v[2]*v[2] + v[3]*v[3]);
    for (int j = 0; j < 4; j++) v[j] /= nrm;
    double e2[3];
    for (int i = 0; i < 3; i++)
        e2[i] = p2[i][0]*v[0] + p2[i][1]*v[1] + p2[i][2]*v[2] + p2[i][3]*v[3];
    double A[3][3];
    for (int i = 0; i < 3; i++)
        for (int k = 0; k < 3; k++) {
            double s = 0.0;
            for (int j = 0; j < 4; j++) s += p1[i][j] * p1[k][j];
            A[i][k] = s;
        }
    double det = A[0][0]*(A[1][1]*A[2][2] - A[1][2]*A[2][1])
               - A[0][1]*(A[1][0]*A[2][2] - A[1][2]*A[2][0])
               + A[0][2]*(A[1][0]*A[2][1] - A[1][1]*A[2][0]);
    double Ai[3][3];
    Ai[0][0] =  (A[1][1]*A[2][2] - A[1][2]*A[2][1]) / det;
    Ai[0][1] = -(A[0][1]*A[2][2] - A[0][2]*A[2][1]) / det;
    Ai[0][2] =  (A[0][1]*A[1][2] - A[0][2]*A[1][1]) / det;
    Ai[1][0] = -(A[1][0]*A[2][2] - A[1][2]*A[2][0]) / det;
    Ai[1][1] =  (A[0][0]*A[2][2] - A[0][2]*A[2][0]) / det;
    Ai[1][2] = -(A[0][0]*A[1][2] - A[0][2]*A[1][0]) / det;
    Ai[2][0] =  (A[1][0]*A[2][1] - A[1][1]*A[2][0]) / det;
    Ai[2][1] = -(A[0][0]*A[2][1] - A[0][1]*A[2][0]) / det;
    Ai[2][2] =  (A[0][0]*A[1][1] - A[0][1]*A[1][0]) / det;
    double B[3][3];
    for (int i = 0; i < 3; i++)
        for (int m = 0; m < 3; m++) {
            double s = 0.0;
            for (int k = 0; k < 4; k++) s += p2[i][k] * p1[m][k];
            B[i][m] = s;
        }
    double G[3][3];
    for (int i = 0; i < 3; i++)
        for (int j = 0; j < 3; j++)
            G[i][j] = B[i][0]*Ai[0][j] + B[i][1]*Ai[1][j] + B[i][2]*Ai[2][j];
    double F[3][3];
    for (int j = 0; j < 3; j++) {
        F[0][j] = -e2[2]*G[1][j] + e2[1]*G[2][j];
        F[1][j] =  e2[2]*G[0][j] - e2[0]*G[2][j];
        F[2][j] = -e2[1]*G[0][j] + e2[0]*G[1][j];
    }
    for (int i = 0; i < 3; i++)
        for (int j = 0; j < 3; j++) Fout[n * 9 + i * 3 + j] = F[i][j];
}

__device__ __forceinline__ unsigned short f2h_u16(float x) {
    union { _Float16 h; unsigned short u; } t;
    t.h = (_Float16)x;   // RNE
    return t.u;
}

// Fused: (N,C,H,W) fp32 -> (N,H*W,C) f16 transpose; block 0 also computes F.
__global__ void transpose_F_kernel(const float* __restrict__ in,
                                   unsigned short* __restrict__ outp,
                                   const float* __restrict__ P1,
                                   const float* __restrict__ P2,
                                   double* __restrict__ Fout) {
    __shared__ float tile[32][33];
    const int n  = blockIdx.z;
    const int p0 = blockIdx.x * 32;
    const int c0 = blockIdx.y * 32;
    const int tx = threadIdx.x, ty = threadIdx.y;

    if (blockIdx.x == 0 && blockIdx.y == 0 && blockIdx.z == 0) {
        const int t = ty * 32 + tx;
        if (t < N_BATCH) compute_F_one(P1, P2, t, Fout);
    }

    for (int i = ty; i < 32; i += 8)
        tile[i][tx] = in[((size_t)n * C_CH + c0 + i) * HW + p0 + tx];
    __syncthreads();

    // write packed pairs of f16 (uint)
    const int t = ty * 32 + tx;
    unsigned* outw = (unsigned*)(outp + ((size_t)n * HW + p0) * C_CH + c0);
    #pragma unroll
    for (int r = 0; r < 2; r++) {
        const int u  = t + r * 256;     // uint index in [0,512)
        const int i  = u >> 4;          // pixel within tile
        const int cp = u & 15;          // channel pair
        const unsigned lo = (unsigned)f2h_u16(tile[2 * cp][i]);
        const unsigned hi = (unsigned)f2h_u16(tile[2 * cp + 1][i]);
        outw[(size_t)i * (C_CH / 2) + cp] = lo | (hi << 16);
    }
}

__device__ __forceinline__ h2 u2h2(unsigned u) {
    union { unsigned u; h2 h; } t; t.u = u; return t.h;
}

// Block = 8 consecutive pixels in one row; 4 waves; each wave serves 2 pixels
// (half-wave per pixel). Lane owns 8 f16 channels (one 16B load per tap).
// Per sample: 2 LDS reads + 4 wave-loads (covering 2 pixels) + packed-f16 math.
__global__ __launch_bounds__(256, 4) void sample_max_f16_kernel(
    const unsigned short* __restrict__ feat,
    const double* __restrict__ Fm,
    float* __restrict__ out) {
    const int bid    = blockIdx.x;        // [0, 1024)
    const int n      = bid >> 9;          // 512 blocks per batch
    const int p_base = (bid & 511) << 3;  // 8-pixel group within one row
    const int h      = p_base >> 6;
    const int w0     = p_base & 63;
    const int tid    = threadIdx.x;       // [0, 256)
    const int wid    = tid >> 6;          // wave id 0..3
    const int lane   = tid & 63;

    __shared__ int4  s_off[PPB][S_SAMP];   // tap byte offsets (cell * 512)
    __shared__ uint4 s_wtp[PPB][S_SAMP];   // packed duplicated-f16 weights
    __shared__ float s_res[PPB][C_CH + 8];

    // ---- per-(pixel,sample) setup (fp64, matches np reference) ----
    #pragma unroll
    for (int r = 0; r < 2; r++) {
        const int u  = tid + (r << 8);    // [0, 512)
        const int j  = u >> 6;            // local pixel 0..7
        const int sl = u & 63;            // sample 0..63
        const int w = w0 + j;
        const double* F = Fm + n * 9;
        const double wd = (double)w, hd = (double)h;
        const double a = F[0]*wd + F[1]*hd + F[2];
        const double b = F[3]*wd + F[4]*hd + F[5];
        const double c = F[6]*wd + F[7]*hd + F[8];
        const double EPSd = 0.001;
        const double xmaxv = 63.0, ymaxv = 63.0;
        const double sb = (b > 0.0) ? 1.0 : ((b < 0.0) ? -1.0 : 0.0);
        const double sa = (a > 0.0) ? 1.0 : ((a < 0.0) ? -1.0 : 0.0);
        const double db = sb * fmax(fabs(b), EPSd);
        const double da = sa * fmax(fabs(a), EPSd);
        const double by1 = -c / db;
        const double by2 = -(xmaxv * a + c) / db;
        const double bx0 = -c / da;
        const double bx3 = -(ymaxv * b + c) / da;
        const double PX[4] = {bx0, 0.0, xmaxv, bx3};
        const double PY[4] = {0.0, by1, by2, ymaxv};
        bool m[4];
        m[0] = (bx0 >= EPSd) && (bx0 <  xmaxv - EPSd);
        m[1] = (by1 >  EPSd) && (by1 <= ymaxv - EPSd);
        m[2] = (by2 >= EPSd) && (by2 <  ymaxv - EPSd);
        m[3] = (bx3 >  EPSd) && (bx3 <= xmaxv - EPSd);
        const int nint = (int)m[0] + (int)m[1] + (int)m[2] + (int)m[3];
        const bool valid2 = (nint >= 2);
        bool tm[4];
        if (valid2) { tm[0]=m[0]; tm[1]=m[1]; tm[2]=m[2]; tm[3]=m[3]; }
        else        { tm[0]=true; tm[1]=true; tm[2]=false; tm[3]=false; }
        int i0 = -1, i1 = -1;
        for (int i = 0; i < 4; i++) if (tm[i])  { if (i0 < 0) i0 = i; else if (i1 < 0) i1 = i; }
        for (int i = 0; i < 4; i++) if (!tm[i]) { if (i0 < 0) i0 = i; else if (i1 < 0) i1 = i; }
        double sx, sy, vx, vy;
        if (valid2) { sx = PX[i0]; sy = PY[i0]; vx = PX[i1] - sx; vy = PY[i1] - sy; }
        else        { sx = -10000.0; sy = -10000.0; vx = 0.0; vy = 0.0; }

        const double t  = (double)sl / 63.0;
        const double lx = sx + vx * t;
        const double ly = sy + vy * t;
        const double gx = lx / 63.0 * 2.0 - 1.0;
        const double gy = ly / 63.0 * 2.0 - 1.0;
        const double x  = (gx + 1.0) * 32.0 - 0.5;
        const double y  = (gy + 1.0) * 32.0 - 0.5;
        const double x0 = floor(x), y0 = floor(y);
        const double wx = x - x0,  wy = y - y0;
        const double wt4[4] = {(1.0-wx)*(1.0-wy), wx*(1.0-wy), (1.0-wx)*wy, wx*wy};
        int      offs[4];
        unsigned wpk[4];
        #pragma unroll
        for (int k = 0; k < 4; k++) {
            const double ix = x0 + (double)(k & 1);
            const double iy = y0 + (double)(k >> 1);
            const bool val = (ix >= 0.0) && (ix < 64.0) && (iy >= 0.0) && (iy < 64.0);
            const double ixc = fmin(fmax(ix, 0.0), 63.0);
            const double iyc = fmin(fmax(iy, 0.0), 63.0);
            offs[k] = (((int)iyc) * 64 + (int)ixc) * (C_CH * 2);  // byte offset, NHWC f16
            const float wf = val ? (float)wt4[k] : 0.0f;
            const unsigned us = (unsigned)f2h_u16(wf);
            wpk[k] = us | (us << 16);
        }
        s_off[j][sl] = make_int4(offs[0], offs[1], offs[2], offs[3]);
        s_wtp[j][sl] = make_uint4(wpk[0], wpk[1], wpk[2], wpk[3]);
    }
    __syncthreads();

    // ---- gather + packed bilinear + max over samples ----
    const int lane5 = lane & 31;
    const int j     = (wid << 1) | (lane >> 5);     // local pixel served by this half-wave
    const char* base = (const char*)(feat + (size_t)n * HW * C_CH) + lane5 * 16; // 8 ch f16

    h2 acc0 = (h2)(_Float16)(-60000.0f);
    h2 acc1 = acc0, acc2 = acc0, acc3 = acc0;

    #pragma unroll 4
    for (int s = 0; s < S_SAMP; s++) {
        const int4  o  = s_off[j][s];
        const uint4 wp = s_wtp[j][s];
        const uint4 va = *(const uint4*)(base + o.x);
        const uint4 vb = *(const uint4*)(base + o.y);
        const uint4 vc = *(const uint4*)(base + o.z);
        const uint4 vd = *(const uint4*)(base + o.w);
        const h2 wa = u2h2(wp.x), wb = u2h2(wp.y), wc = u2h2(wp.z), wd = u2h2(wp.w);
        const h2 r0 = u2h2(va.x)*wa + u2h2(vb.x)*wb + u2h2(vc.x)*wc + u2h2(vd.x)*wd;
        const h2 r1 = u2h2(va.y)*wa + u2h2(vb.y)*wb + u2h2(vc.y)*wc + u2h2(vd.y)*wd;
        const h2 r2 = u2h2(va.z)*wa + u2h2(vb.z)*wb + u2h2(vc.z)*wc + u2h2(vd.z)*wd;
        const h2 r3 = u2h2(va.w)*wa + u2h2(vb.w)*wb + u2h2(vc.w)*wc + u2h2(vd.w)*wd;
        acc0 = __builtin_elementwise_max(acc0, r0);
        acc1 = __builtin_elementwise_max(acc1, r1);
        acc2 = __builtin_elementwise_max(acc2, r2);
        acc3 = __builtin_elementwise_max(acc3, r3);
    }

    // ---- stage results (f32), then coalesced-ish write ----
    {
        const int cb = lane5 * 8;
        s_res[j][cb + 0] = (float)acc0.x;
        s_res[j][cb + 1] = (float)acc0.y;
        s_res[j][cb + 2] = (float)acc1.x;
        s_res[j][cb + 3] = (float)acc1.y;
        s_res[j][cb + 4] = (float)acc2.x;
        s_res[j][cb + 5] = (float)acc2.y;
        s_res[j][cb + 6] = (float)acc3.x;
        s_res[j][cb + 7] = (float)acc3.y;
    }
    __syncthreads();
    {
        const int jj = tid & 7;    // pixel within group
        const int c0 = tid >> 3;   // 0..31
        const size_t obase = (size_t)n * C_CH * HW + h * 64 + w0 + jj;
        #pragma unroll
        for (int k = 0; k < 8; k++) {
            const int c = c0 + (k << 5);
            out[obase + (size_t)c * HW] = s_res[jj][c];
        }
    }
}

// Fallback (no workspace): direct fp32 gather from (N,C,H,W), 1 wave per pixel.
__global__ __launch_bounds__(64) void sample_max_fallback_kernel(
    const float* __restrict__ feat, const double* __restrict__ Fm,
    float* __restrict__ out) {
    const int bid  = blockIdx.x;
    const int n    = bid >> 12;
    const int p    = bid & 4095;
    const int h    = p >> 6;
    const int w    = p & 63;
    const int lane = threadIdx.x;
    __shared__ int4   s_off[S_SAMP];
    __shared__ float4 s_wt[S_SAMP];
    {
        const double* F = Fm + n * 9;
        const double wd = (double)w, hd = (double)h;
        const double a = F[0]*wd + F[1]*hd + F[2];
        const double b = F[3]*wd + F[4]*hd + F[5];
        const double c = F[6]*wd + F[7]*hd + F[8];
        const double EPSd = 0.001;
        const double xmaxv = 63.0, ymaxv = 63.0;
        const double sb = (b > 0.0) ? 1.0 : ((b < 0.0) ? -1.0 : 0.0);
        const double sa = (a > 0.0) ? 1.0 : ((a < 0.0) ? -1.0 : 0.0);
        const double db = sb * fmax(fabs(b), EPSd);
        const double da = sa * fmax(fabs(a), EPSd);
        const double by1 = -c / db;
        const double by2 = -(xmaxv * a + c) / db;
        const double bx0 = -c / da;
        const double bx3 = -(ymaxv * b + c) / da;
        const double PX[4] = {bx0, 0.0, xmaxv, bx3};
        const double PY[4] = {0.0, by1, by2, ymaxv};
        bool m[4];
        m[0] = (bx0 >= EPSd) && (bx0 <  xmaxv - EPSd);
        m[1] = (by1 >  EPSd) && (by1 <= ymaxv - EPSd);
        m[2] = (by2 >= EPSd) && (by2 <  ymaxv - EPSd);
        m[3] = (bx3 >  EPSd) && (bx3 <= xmaxv - EPSd);
        const int nint = (int)m[0] + (int)m[1] + (int)m[2] + (int)m[3];
        const bool valid2 = (nint >= 2);
        bool tm[4];
        if (valid2) { tm[0]=m[0]; tm[1]=m[1]; tm[2]=m[2]; tm[3]=m[3]; }
        else        { tm[0]=true; tm[1]=true; tm[2]=false; tm[3]=false; }
        int i0 = -1, i1 = -1;
        for (int i = 0; i < 4; i++) if (tm[i])  { if (i0 < 0) i0 = i; else if (i1 < 0) i1 = i; }
        for (int i = 0; i < 4; i++) if (!tm[i]) { if (i0 < 0) i0 = i; else if (i1 < 0) i1 = i; }
        double sx, sy, vx, vy;
        if (valid2) { sx = PX[i0]; sy = PY[i0]; vx = PX[i1] - sx; vy = PY[i1] - sy; }
        else        { sx = -10000.0; sy = -10000.0; vx = 0.0; vy = 0.0; }
        const double t  = (double)lane / 63.0;
        const double lx = sx + vx * t;
        const double ly = sy + vy * t;
        const double gx = lx / 63.0 * 2.0 - 1.0;
        const double gy = ly / 63.0 * 2.0 - 1.0;
        const double x  = (gx + 1.0) * 32.0 - 0.5;
        const double y  = (gy + 1.0) * 32.0 - 0.5;
        const double x0 = floor(x), y0 = floor(y);
        const double wx = x - x0,  wy = y - y0;
        const double wt4[4] = {(1.0-wx)*(1.0-wy), wx*(1.0-wy), (1.0-wx)*wy, wx*wy};
        int   offs[4];
        float wts[4];
        #pragma unroll
        for (int k = 0; k < 4; k++) {
            const double ix = x0 + (double)(k & 1);
            const double iy = y0 + (double)(k >> 1);
            const bool val = (ix >= 0.0) && (ix < 64.0) && (iy >= 0.0) && (iy < 64.0);
            const double ixc = fmin(fmax(ix, 0.0), 63.0);
            const double iyc = fmin(fmax(iy, 0.0), 63.0);
            offs[k] = ((int)iyc) * 64 + (int)ixc;
            wts[k]  = val ? (float)wt4[k] : 0.0f;
        }
        s_off[lane] = make_int4(offs[0], offs[1], offs[2], offs[3]);
        s_wt[lane]  = make_float4(wts[0], wts[1], wts[2], wts[3]);
    }
    __syncthreads();
    const float* base = feat + (size_t)n * (size_t)HW * C_CH;
    float mx0 = -INFINITY, mx1 = -INFINITY, mx2 = -INFINITY, mx3 = -INFINITY;
    const int cb = lane * 4;
    for (int s = 0; s < S_SAMP; s++) {
        const int4   o  = s_off[s];
        const float4 wv = s_wt[s];
        float4 v0 = make_float4(base[(size_t)(cb+0)*HW + o.x], base[(size_t)(cb+1)*HW + o.x],
                                base[(size_t)(cb+2)*HW + o.x], base[(size_t)(cb+3)*HW + o.x]);
        float4 v1 = make_float4(base[(size_t)(cb+0)*HW + o.y], base[(size_t)(cb+1)*HW + o.y],
                                base[(size_t)(cb+2)*HW + o.y], base[(size_t)(cb+3)*HW + o.y]);
        float4 v2 = make_float4(base[(size_t)(cb+0)*HW + o.z], base[(size_t)(cb+1)*HW + o.z],
                                base[(size_t)(cb+2)*HW + o.z], base[(size_t)(cb+3)*HW + o.z]);
        float4 v3 = make_float4(base[(size_t)(cb+0)*HW + o.w], base[(size_t)(cb+1)*HW + o.w],
                                base[(size_t)(cb+2)*HW + o.w], base[(size_t)(cb+3)*HW + o.w]);
        mx0 = fmaxf(mx0, wv.x*v0.x + wv.y*v1.x + wv.z*v2.x + wv.w*v3.x);
        mx1 = fmaxf(mx1, wv.x*v0.y + wv.y*v1.y + wv.z*v2.y + wv.w*v3.y);
        mx2 = fmaxf(mx2, wv.x*v0.z + wv.y*v1.z + wv.z*v2.z + wv.w*v3.z);
        mx3 = fmaxf(mx3, wv.x*v0.w + wv.y*v1.w + wv.z*v2.w + wv.w*v3.w);
    }
    const int ob = ((n * C_CH + cb) * H_IMG + h) * W_IMG + w;
    out[ob]        = mx0;
    out[ob + HW]   = mx1;
    out[ob + 2*HW] = mx2;
    out[ob + 3*HW] = mx3;
}

__global__ void compute_F_only_kernel(const float* __restrict__ P1,
                                      const float* __restrict__ P2,
                                      double* __restrict__ Fout) {
    int n = threadIdx.x;
    if (n < N_BATCH) compute_F_one(P1, P2, n, Fout);
}

extern "C" void kernel_launch(void* const* d_in, const int* in_sizes, int n_in,
                              void* d_out, int out_size, void* d_ws, size_t ws_size,
                              hipStream_t stream) {
    const float* feat2 = (const float*)d_in[1];
    const float* P1    = (const float*)d_in[2];
    const float* P2    = (const float*)d_in[3];
    float* out = (float*)d_out;

    const size_t ft_bytes = (size_t)N_BATCH * HW * C_CH * sizeof(unsigned short); // 4 MB
    const bool use_t = (ws_size >= ft_bytes + 256);

    if (use_t) {
        unsigned short* ft = (unsigned short*)d_ws;
        double* Fm = (double*)((char*)d_ws + ft_bytes);
        dim3 tb(32, 8);
        dim3 tg(HW / 32, C_CH / 32, N_BATCH);
        transpose_F_kernel<<<tg, tb, 0, stream>>>(feat2, ft, P1, P2, Fm);
        sample_max_f16_kernel<<<(N_BATCH * HW) / PPB, 256, 0, stream>>>(ft, Fm, out);
    } else {
        double* Fm = (double*)d_ws;
        compute_F_only_kernel<<<1, 64, 0, stream>>>(P1, P2, Fm);
        sample_max_fallback_kernel<<<N_BATCH * HW, 64, 0, stream>>>(feat2, Fm, out);
    }
}

// Round 6
// 106.417 us; speedup vs baseline: 1.3409x; 1.0138x over previous
//
#include <hip/hip_runtime.h>
#include <math.h>

#define N_BATCH 2
#define C_CH    256
#define H_IMG   64
#define W_IMG   64
#define S_SAMP  64
#define HW      (H_IMG * W_IMG)
#define PPB     8                       // pixels per block (4 waves, 2 px/wave)
#define CELL_B  (C_CH * 2)              // 512 bytes per pixel-cell (256 ch f16)
#define ROW_B   (W_IMG * CELL_B)        // 32768 bytes per image row
#define IMG_B   ((size_t)HW * CELL_B)   // 4 MB per image
#define FT_GUARD 65536                  // front guard for negative stray reads

typedef _Float16 h2 __attribute__((ext_vector_type(2)));

// det of 3x3 with columns u, v, w
__device__ __forceinline__ double det3(const double* u, const double* v, const double* w) {
    return u[0] * (v[1] * w[2] - v[2] * w[1])
         - v[0] * (u[1] * w[2] - u[2] * w[1])
         + w[0] * (u[1] * v[2] - u[2] * v[1]);
}

// F = skew(P2 @ Cc) @ P2 @ pinv(P1), fp64. Cc = unit null vector of P1 (== eigh
// smallest eigenvector up to sign; sign cancels downstream). pinv via P1^T (P1 P1^T)^-1.
__device__ void compute_F_one(const float* __restrict__ P1g,
                              const float* __restrict__ P2g,
                              int n, double* __restrict__ Fout) {
    double p1[3][4], p2[3][4];
    for (int i = 0; i < 3; i++)
        for (int j = 0; j < 4; j++) {
            p1[i][j] = (double)P1g[n * 12 + i * 4 + j];
            p2[i][j] = (double)P2g[n * 12 + i * 4 + j];
        }
    double col[4][3];
    for (int j = 0; j < 4; j++)
        for (int i = 0; i < 3; i++) col[j][i] = p1[i][j];
    const int idx[4][3] = {{1,2,3},{0,2,3},{0,1,3},{0,1,2}};
    double v[4];
    double sgn = 1.0;
    for (int j = 0; j < 4; j++) {
        v[j] = sgn * det3(col[idx[j][0]], col[idx[j][1]], col[idx[j][2]]);
        sgn = -sgn;
    }
    double nrm = sqrt(v[0]*v[0] + v[1]*v[1] + v[2]*v[2] + v[3]*v[3]);
    for (int j = 0; j < 4; j++) v[j] /= nrm;
    double e2[3];
    for (int i = 0; i < 3; i++)
        e2[i] = p2[i][0]*v[0] + p2[i][1]*v[1] + p2[i][2]*v[2] + p2[i][3]*v[3];
    double A[3][3];
    for (int i = 0; i < 3; i++)
        for (int k = 0; k < 3; k++) {
            double s = 0.0;
            for (int j = 0; j < 4; j++) s += p1[i][j] * p1[k][j];
            A[i][k] = s;
        }
    double det = A[0][0]*(A[1][1]*A[2][2] - A[1][2]*A[2][1])
               - A[0][1]*(A[1][0]*A[2][2] - A[1][2]*A[2][0])
               + A[0][2]*(A[1][0]*A[2][1] - A[1][1]*A[2][0]);
    double Ai[3][3];
    Ai[0][0] =  (A[1][1]*A[2][2] - A[1][2]*A[2][1]) / det;
    Ai[0][1] = -(A[0][1]*A[2][2] - A[0][2]*A[2][1]) / det;
    Ai[0][2] =  (A[0][1]*A[1][2] - A[0][2]*A[1][1]) / det;
    Ai[1][0] = -(A[1][0]*A[2][2] - A[1][2]*A[2][0]) / det;
    Ai[1][1] =  (A[0][0]*A[2][2] - A[0][2]*A[2][0]) / det;
    Ai[1][2] = -(A[0][0]*A[1][2] - A[0][2]*A[1][0]) / det;
    Ai[2][0] =  (A[1][0]*A[2][1] - A[1][1]*A[2][0]) / det;
    Ai[2][1] = -(A[0][0]*A[2][1] - A[0][1]*A[2][0]) / det;
    Ai[2][2] =  (A[0][0]*A[1][1] - A[0][1]*A[1][0]) / det;
    double B[3][3];
    for (int i = 0; i < 3; i++)
        for (int m = 0; m < 3; m++) {
            double s = 0.0;
            for (int k = 0; k < 4; k++) s += p2[i][k] * p1[m][k];
            B[i][m] = s;
        }
    double G[3][3];
    for (int i = 0; i < 3; i++)
        for (int j = 0; j < 3; j++)
            G[i][j] = B[i][0]*Ai[0][j] + B[i][1]*Ai[1][j] + B[i][2]*Ai[2][j];
    double F[3][3];
    for (int j = 0; j < 3; j++) {
        F[0][j] = -e2[2]*G[1][j] + e2[1]*G[2][j];
        F[1][j] =  e2[2]*G[0][j] - e2[0]*G[2][j];
        F[2][j] = -e2[1]*G[0][j] + e2[0]*G[1][j];
    }
    for (int i = 0; i < 3; i++)
        for (int j = 0; j < 3; j++) Fout[n * 9 + i * 3 + j] = F[i][j];
}

__device__ __forceinline__ unsigned short f2h_u16(float x) {
    union { _Float16 h; unsigned short u; } t;
    t.h = (_Float16)x;   // RNE
    return t.u;
}

// Fused: (N,C,H,W) fp32 -> (N,H*W,C) f16 transpose (vectorized reads);
// block 0 also computes F.
__global__ __launch_bounds__(256) void transpose_F_kernel(
    const float* __restrict__ in, unsigned short* __restrict__ outp,
    const float* __restrict__ P1, const float* __restrict__ P2,
    double* __restrict__ Fout) {
    __shared__ float tile[32][36];
    const int n  = blockIdx.z;
    const int p0 = blockIdx.x * 32;
    const int c0 = blockIdx.y * 32;
    const int t  = threadIdx.x;

    if (blockIdx.x == 0 && blockIdx.y == 0 && blockIdx.z == 0) {
        if (t < N_BATCH) compute_F_one(P1, P2, t, Fout);
    }

    {
        const int ch  = t >> 3;          // 0..31
        const int px4 = (t & 7) * 4;     // 0,4,..,28
        const float4 v = *(const float4*)(in + ((size_t)n * C_CH + c0 + ch) * HW + p0 + px4);
        *(float4*)&tile[ch][px4] = v;
    }
    __syncthreads();

    unsigned* outw = (unsigned*)(outp + ((size_t)n * HW + p0) * C_CH + c0);
    #pragma unroll
    for (int r = 0; r < 2; r++) {
        const int u  = t + r * 256;     // uint index in [0,512)
        const int i  = u >> 4;          // pixel within tile
        const int cp = u & 15;          // channel pair
        const unsigned lo = (unsigned)f2h_u16(tile[2 * cp][i]);
        const unsigned hi = (unsigned)f2h_u16(tile[2 * cp + 1][i]);
        outw[(size_t)i * (C_CH / 2) + cp] = lo | (hi << 16);
    }
}

__device__ __forceinline__ h2 u2h2(unsigned u) {
    union { unsigned u; h2 h; } t; t.u = u; return t.h;
}

// Block = 8 consecutive pixels in one row; 4 waves; each wave serves 2 pixels
// (half-wave per pixel). Lane owns 8 f16 channels (one 16B load per tap).
// Taps are at FIXED relative offsets from one base cell (+512B, +ROW_B,
// +ROW_B+512B); out-of-range taps have weight 0 so their (in-bounds, thanks to
// the front guard) garbage value never matters.
__global__ __launch_bounds__(256, 4) void sample_max_f16_kernel(
    const unsigned short* __restrict__ feat,   // = d_ws + FT_GUARD
    const double* __restrict__ Fm,
    float* __restrict__ out) {
    const int bid    = blockIdx.x;        // [0, 1024)
    const int n      = bid >> 9;          // 512 blocks per batch
    const int p_base = (bid & 511) << 3;  // 8-pixel group within one row
    const int h      = p_base >> 6;
    const int w0     = p_base & 63;
    const int tid    = threadIdx.x;       // [0, 256)
    const int wid    = tid >> 6;          // wave id 0..3
    const int lane   = tid & 63;

    __shared__ int   s_boff[PPB][S_SAMP];  // base tap byte offset (can be negative)
    __shared__ uint4 s_wtp [PPB][S_SAMP];  // packed duplicated-f16 weights
    __shared__ float s_res [PPB][C_CH + 8];

    // ---- per-(pixel,sample) setup (fp64, matches np reference) ----
    #pragma unroll
    for (int r = 0; r < 2; r++) {
        const int u  = tid + (r << 8);    // [0, 512)
        const int j  = u >> 6;            // local pixel 0..7
        const int sl = u & 63;            // sample 0..63
        const int w = w0 + j;
        const double* F = Fm + n * 9;
        const double wd = (double)w, hd = (double)h;
        const double a = F[0]*wd + F[1]*hd + F[2];
        const double b = F[3]*wd + F[4]*hd + F[5];
        const double c = F[6]*wd + F[7]*hd + F[8];
        const double EPSd = 0.001;
        const double xmaxv = 63.0, ymaxv = 63.0;
        const double sb = (b > 0.0) ? 1.0 : ((b < 0.0) ? -1.0 : 0.0);
        const double sa = (a > 0.0) ? 1.0 : ((a < 0.0) ? -1.0 : 0.0);
        const double db = sb * fmax(fabs(b), EPSd);
        const double da = sa * fmax(fabs(a), EPSd);
        const double by1 = -c / db;
        const double by2 = -(xmaxv * a + c) / db;
        const double bx0 = -c / da;
        const double bx3 = -(ymaxv * b + c) / da;
        const double PX[4] = {bx0, 0.0, xmaxv, bx3};
        const double PY[4] = {0.0, by1, by2, ymaxv};
        bool m[4];
        m[0] = (bx0 >= EPSd) && (bx0 <  xmaxv - EPSd);
        m[1] = (by1 >  EPSd) && (by1 <= ymaxv - EPSd);
        m[2] = (by2 >= EPSd) && (by2 <  ymaxv - EPSd);
        m[3] = (bx3 >  EPSd) && (bx3 <= xmaxv - EPSd);
        const int nint = (int)m[0] + (int)m[1] + (int)m[2] + (int)m[3];
        const bool valid2 = (nint >= 2);
        bool tm[4];
        if (valid2) { tm[0]=m[0]; tm[1]=m[1]; tm[2]=m[2]; tm[3]=m[3]; }
        else        { tm[0]=true; tm[1]=true; tm[2]=false; tm[3]=false; }
        int i0 = -1, i1 = -1;
        for (int i = 0; i < 4; i++) if (tm[i])  { if (i0 < 0) i0 = i; else if (i1 < 0) i1 = i; }
        for (int i = 0; i < 4; i++) if (!tm[i]) { if (i0 < 0) i0 = i; else if (i1 < 0) i1 = i; }
        double sx, sy, vx, vy;
        if (valid2) { sx = PX[i0]; sy = PY[i0]; vx = PX[i1] - sx; vy = PY[i1] - sy; }
        else        { sx = -10000.0; sy = -10000.0; vx = 0.0; vy = 0.0; }

        const double t  = (double)sl / 63.0;
        const double lx = sx + vx * t;
        const double ly = sy + vy * t;
        const double gx = lx / 63.0 * 2.0 - 1.0;
        const double gy = ly / 63.0 * 2.0 - 1.0;
        const double x  = (gx + 1.0) * 32.0 - 0.5;
        const double y  = (gy + 1.0) * 32.0 - 0.5;
        const double x0 = floor(x), y0 = floor(y);
        const double wx = x - x0,  wy = y - y0;
        const double wt4[4] = {(1.0-wx)*(1.0-wy), wx*(1.0-wy), (1.0-wx)*wy, wx*wy};
        // base cell clamped to [-1,63]^2 (only bites for the invalid-segment
        // case, where all weights are 0); valid samples have x0,y0 in [-1,63].
        const double bxd = fmin(fmax(x0, -1.0), 63.0);
        const double byd = fmin(fmax(y0, -1.0), 63.0);
        const int base_off = (((int)byd) * 64 + (int)bxd) * CELL_B;
        unsigned wpk[4];
        #pragma unroll
        for (int k = 0; k < 4; k++) {
            const double ix = x0 + (double)(k & 1);
            const double iy = y0 + (double)(k >> 1);
            const bool val = (ix >= 0.0) && (ix < 64.0) && (iy >= 0.0) && (iy < 64.0);
            const float wf = val ? (float)wt4[k] : 0.0f;
            const unsigned us = (unsigned)f2h_u16(wf);
            wpk[k] = us | (us << 16);
        }
        s_boff[j][sl] = base_off;
        s_wtp [j][sl] = make_uint4(wpk[0], wpk[1], wpk[2], wpk[3]);
    }
    __syncthreads();

    // ---- gather + packed bilinear + max over samples ----
    const int lane5 = lane & 31;
    const int j     = (wid << 1) | (lane >> 5);     // local pixel served by this half-wave
    const char* base = (const char*)feat + (size_t)n * IMG_B + lane5 * 16; // 8 ch f16

    h2 acc0 = (h2)(_Float16)(-60000.0f);
    h2 acc1 = acc0, acc2 = acc0, acc3 = acc0;

    #pragma unroll 4
    for (int s = 0; s < S_SAMP; s++) {
        const int   bo = s_boff[j][s];
        const uint4 wp = s_wtp[j][s];
        const char* pa = base + bo;
        const uint4 va = *(const uint4*)(pa);
        const uint4 vb = *(const uint4*)(pa + CELL_B);
        const uint4 vc = *(const uint4*)(pa + ROW_B);
        const uint4 vd = *(const uint4*)(pa + ROW_B + CELL_B);
        const h2 wa = u2h2(wp.x), wb = u2h2(wp.y), wc = u2h2(wp.z), wd = u2h2(wp.w);
        const h2 r0 = u2h2(va.x)*wa + u2h2(vb.x)*wb + u2h2(vc.x)*wc + u2h2(vd.x)*wd;
        const h2 r1 = u2h2(va.y)*wa + u2h2(vb.y)*wb + u2h2(vc.y)*wc + u2h2(vd.y)*wd;
        const h2 r2 = u2h2(va.z)*wa + u2h2(vb.z)*wb + u2h2(vc.z)*wc + u2h2(vd.z)*wd;
        const h2 r3 = u2h2(va.w)*wa + u2h2(vb.w)*wb + u2h2(vc.w)*wc + u2h2(vd.w)*wd;
        acc0 = __builtin_elementwise_max(acc0, r0);
        acc1 = __builtin_elementwise_max(acc1, r1);
        acc2 = __builtin_elementwise_max(acc2, r2);
        acc3 = __builtin_elementwise_max(acc3, r3);
    }

    // ---- stage results (f32), then write out ----
    {
        const int cb = lane5 * 8;
        s_res[j][cb + 0] = (float)acc0.x;
        s_res[j][cb + 1] = (float)acc0.y;
        s_res[j][cb + 2] = (float)acc1.x;
        s_res[j][cb + 3] = (float)acc1.y;
        s_res[j][cb + 4] = (float)acc2.x;
        s_res[j][cb + 5] = (float)acc2.y;
        s_res[j][cb + 6] = (float)acc3.x;
        s_res[j][cb + 7] = (float)acc3.y;
    }
    __syncthreads();
    {
        const int jj = tid & 7;    // pixel within group
        const int c0 = tid >> 3;   // 0..31
        const size_t obase = (size_t)n * C_CH * HW + h * 64 + w0 + jj;
        #pragma unroll
        for (int k = 0; k < 8; k++) {
            const int c = c0 + (k << 5);
            out[obase + (size_t)c * HW] = s_res[jj][c];
        }
    }
}

// Fallback (no workspace): direct fp32 gather from (N,C,H,W), 1 wave per pixel.
__global__ __launch_bounds__(64) void sample_max_fallback_kernel(
    const float* __restrict__ feat, const double* __restrict__ Fm,
    float* __restrict__ out) {
    const int bid  = blockIdx.x;
    const int n    = bid >> 12;
    const int p    = bid & 4095;
    const int h    = p >> 6;
    const int w    = p & 63;
    const int lane = threadIdx.x;
    __shared__ int4   s_off[S_SAMP];
    __shared__ float4 s_wt[S_SAMP];
    {
        const double* F = Fm + n * 9;
        const double wd = (double)w, hd = (double)h;
        const double a = F[0]*wd + F[1]*hd + F[2];
        const double b = F[3]*wd + F[4]*hd + F[5];
        const double c = F[6]*wd + F[7]*hd + F[8];
        const double EPSd = 0.001;
        const double xmaxv = 63.0, ymaxv = 63.0;
        const double sb = (b > 0.0) ? 1.0 : ((b < 0.0) ? -1.0 : 0.0);
        const double sa = (a > 0.0) ? 1.0 : ((a < 0.0) ? -1.0 : 0.0);
        const double db = sb * fmax(fabs(b), EPSd);
        const double da = sa * fmax(fabs(a), EPSd);
        const double by1 = -c / db;
        const double by2 = -(xmaxv * a + c) / db;
        const double bx0 = -c / da;
        const double bx3 = -(ymaxv * b + c) / da;
        const double PX[4] = {bx0, 0.0, xmaxv, bx3};
        const double PY[4] = {0.0, by1, by2, ymaxv};
        bool m[4];
        m[0] = (bx0 >= EPSd) && (bx0 <  xmaxv - EPSd);
        m[1] = (by1 >  EPSd) && (by1 <= ymaxv - EPSd);
        m[2] = (by2 >= EPSd) && (by2 <  ymaxv - EPSd);
        m[3] = (bx3 >  EPSd) && (bx3 <= xmaxv - EPSd);
        const int nint = (int)m[0] + (int)m[1] + (int)m[2] + (int)m[3];
        const bool valid2 = (nint >= 2);
        bool tm[4];
        if (valid2) { tm[0]=m[0]; tm[1]=m[1]; tm[2]=m[2]; tm[3]=m[3]; }
        else        { tm[0]=true; tm[1]=true; tm[2]=false; tm[3]=false; }
        int i0 = -1, i1 = -1;
        for (int i = 0; i < 4; i++) if (tm[i])  { if (i0 < 0) i0 = i; else if (i1 < 0) i1 = i; }
        for (int i = 0; i < 4; i++) if (!tm[i]) { if (i0 < 0) i0 = i; else if (i1 < 0) i1 = i; }
        double sx, sy, vx, vy;
        if (valid2) { sx = PX[i0]; sy = PY[i0]; vx = PX[i1] - sx; vy = PY[i1] - sy; }
        else        { sx = -10000.0; sy = -10000.0; vx = 0.0; vy = 0.0; }
        const double t  = (double)lane / 63.0;
        const double lx = sx + vx * t;
        const double ly = sy + vy * t;
        const double gx = lx / 63.0 * 2.0 - 1.0;
        const double gy = ly / 63.0 * 2.0 - 1.0;
        const double x  = (gx + 1.0) * 32.0 - 0.5;
        const double y  = (gy + 1.0) * 32.0 - 0.5;
        const double x0 = floor(x), y0 = floor(y);
        const double wx = x - x0,  wy = y - y0;
        const double wt4[4] = {(1.0-wx)*(1.0-wy), wx*(1.0-wy), (1.0-wx)*wy, wx*wy};
        int   offs[4];
        float wts[4];
        #pragma unroll
        for (int k = 0; k < 4; k++) {
            const double ix = x0 + (double)(k & 1);
            const double iy = y0 + (double)(k >> 1);
            const bool val = (ix >= 0.0) && (ix < 64.0) && (iy >= 0.0) && (iy < 64.0);
            const double ixc = fmin(fmax(ix, 0.0), 63.0);
            const double iyc = fmin(fmax(iy, 0.0), 63.0);
            offs[k] = ((int)iyc) * 64 + (int)ixc;
            wts[k]  = val ? (float)wt4[k] : 0.0f;
        }
        s_off[lane] = make_int4(offs[0], offs[1], offs[2], offs[3]);
        s_wt[lane]  = make_float4(wts[0], wts[1], wts[2], wts[3]);
    }
    __syncthreads();
    const float* base = feat + (size_t)n * (size_t)HW * C_CH;
    float mx0 = -INFINITY, mx1 = -INFINITY, mx2 = -INFINITY, mx3 = -INFINITY;
    const int cb = lane * 4;
    for (int s = 0; s < S_SAMP; s++) {
        const int4   o  = s_off[s];
        const float4 wv = s_wt[s];
        float4 v0 = make_float4(base[(size_t)(cb+0)*HW + o.x], base[(size_t)(cb+1)*HW + o.x],
                                base[(size_t)(cb+2)*HW + o.x], base[(size_t)(cb+3)*HW + o.x]);
        float4 v1 = make_float4(base[(size_t)(cb+0)*HW + o.y], base[(size_t)(cb+1)*HW + o.y],
                                base[(size_t)(cb+2)*HW + o.y], base[(size_t)(cb+3)*HW + o.y]);
        float4 v2 = make_float4(base[(size_t)(cb+0)*HW + o.z], base[(size_t)(cb+1)*HW + o.z],
                                base[(size_t)(cb+2)*HW + o.z], base[(size_t)(cb+3)*HW + o.z]);
        float4 v3 = make_float4(base[(size_t)(cb+0)*HW + o.w], base[(size_t)(cb+1)*HW + o.w],
                                base[(size_t)(cb+2)*HW + o.w], base[(size_t)(cb+3)*HW + o.w]);
        mx0 = fmaxf(mx0, wv.x*v0.x + wv.y*v1.x + wv.z*v2.x + wv.w*v3.x);
        mx1 = fmaxf(mx1, wv.x*v0.y + wv.y*v1.y + wv.z*v2.y + wv.w*v3.y);
        mx2 = fmaxf(mx2, wv.x*v0.z + wv.y*v1.z + wv.z*v2.z + wv.w*v3.z);
        mx3 = fmaxf(mx3, wv.x*v0.w + wv.y*v1.w + wv.z*v2.w + wv.w*v3.w);
    }
    const int ob = ((n * C_CH + cb) * H_IMG + h) * W_IMG + w;
    out[ob]        = mx0;
    out[ob + HW]   = mx1;
    out[ob + 2*HW] = mx2;
    out[ob + 3*HW] = mx3;
}

__global__ void compute_F_only_kernel(const float* __restrict__ P1,
                                      const float* __restrict__ P2,
                                      double* __restrict__ Fout) {
    int n = threadIdx.x;
    if (n < N_BATCH) compute_F_one(P1, P2, n, Fout);
}

extern "C" void kernel_launch(void* const* d_in, const int* in_sizes, int n_in,
                              void* d_out, int out_size, void* d_ws, size_t ws_size,
                              hipStream_t stream) {
    const float* feat2 = (const float*)d_in[1];
    const float* P1    = (const float*)d_in[2];
    const float* P2    = (const float*)d_in[3];
    float* out = (float*)d_out;

    // layout in d_ws: [0,64K) front guard | images (8 MB) | tail slack | Fm @ 32 MB
    const bool use_t = (ws_size >= (size_t)33 * 1024 * 1024);

    if (use_t) {
        unsigned short* ft = (unsigned short*)((char*)d_ws + FT_GUARD);
        double* Fm = (double*)((char*)d_ws + (size_t)32 * 1024 * 1024);
        dim3 tg(HW / 32, C_CH / 32, N_BATCH);
        transpose_F_kernel<<<tg, 256, 0, stream>>>(feat2, ft, P1, P2, Fm);
        sample_max_f16_kernel<<<(N_BATCH * HW) / PPB, 256, 0, stream>>>(ft, Fm, out);
    } else {
        double* Fm = (double*)d_ws;
        compute_F_only_kernel<<<1, 64, 0, stream>>>(P1, P2, Fm);
        sample_max_fallback_kernel<<<N_BATCH * HW, 64, 0, stream>>>(feat2, Fm, out);
    }
}